// Round 4
// baseline (1094.833 us; speedup 1.0000x reference)
//
#include <hip/hip_runtime.h>
#include <hip/hip_bf16.h>

// ResnetBlockDDPMpp_Adagn: B=8, CIN=COUT=256, H=W=64, G=32, K=3
// Round 3: big convs (deform einsum + conv1) converted to bf16 MFMA 16x16x32.
//  - Block = 32 px x 256 outch, 4 waves; per wave 2 M-tiles x 4 N-tiles.
//  - A (activations) staged in LDS bf16, stride 264 (2-way bank conflicts = free).
//  - B (weights) pre-packed [k][c8][o][8] bf16 -> one contiguous 16B load/lane.
//  - C/D layout (m89-verified): lane holds C[(lane>>4)*4+j][lane&15].
//  - h2 stored bf16 (halves conv1 staging traffic); h0/h1 stay fp32.

#define EPSV 1e-6f

typedef short  bf16x8 __attribute__((ext_vector_type(8)));
typedef float  f32x4  __attribute__((ext_vector_type(4)));

__device__ __forceinline__ float silu_f(float v){ return v / (1.f + __expf(-v)); }
__device__ __forceinline__ unsigned short f2bf(float f){
  unsigned int u = __float_as_uint(f);
  u = (u + 0x7FFFu + ((u >> 16) & 1u)) >> 16;
  return (unsigned short)u;
}

// ---------------- ws layout (float units) ----------------
#define WS_H0      0            // 8*4096*256 fp32 NHWC h0; later reused as h2 bf16
#define WS_H1      8388608      // 8*4096*256 fp32 NHWC
#define WS_OFFT    16777216     // 8*4096*27
#define WS_WTD     17661952     // dcn bf16 [9][32][256][8] = 589824 ushort
#define WS_WTC     17956864     // conv1 bf16 same layout
#define WS_OFFWT   18251776     // 9*256*27 fp32
#define WS_STYLE0  18313984     // 8*512
#define WS_STYLE1  18318080     // 8*512
#define WS_TPROJ   18322176     // 8*256
#define WS_MU0     18324224
#define WS_RS0     18324480
#define WS_MU1     18324736
#define WS_RS1     18324992
// end 18,325,248 floats = 73.3 MB

// ---------- prep: weight packs + tiny GEMMs ----------
__global__ __launch_bounds__(256) void prep_kernel(
    const float* __restrict__ zemb, const float* __restrict__ temb,
    const float* __restrict__ g0w, const float* __restrict__ g0b,
    const float* __restrict__ g1w, const float* __restrict__ g1b,
    const float* __restrict__ d0w, const float* __restrict__ d0b,
    const float* __restrict__ dcn_w, const float* __restrict__ c1w,
    const float* __restrict__ offw,
    unsigned short* __restrict__ wtd, unsigned short* __restrict__ wtc,
    float* __restrict__ off_wt,
    float* __restrict__ style0, float* __restrict__ style1, float* __restrict__ tproj)
{
  int blk = blockIdx.x, t = threadIdx.x;
  if (blk < 2304) {                       // dcn pack: e=((k*32+c8)*256+o)*8+j <- w[o, c8*8+j, k]
    int e = blk*256 + t;
    int j = e & 7, o = (e >> 3) & 255, c8 = (e >> 11) & 31, k = e >> 16;
    wtd[e] = f2bf(dcn_w[((o*256 + c8*8 + j)*9) + k]);
  } else if (blk < 4608) {                // conv1 pack
    int e = (blk-2304)*256 + t;
    int j = e & 7, o = (e >> 3) & 255, c8 = (e >> 11) & 31, k = e >> 16;
    wtc[e] = f2bf(c1w[((o*256 + c8*8 + j)*9) + k]);
  } else if (blk < 4851) {                // offset_w (27,c,3,3) -> [(k*256+c)*27+o] fp32
    int e = (blk-4608)*256 + t;
    if (e < 62208) {
      int o = e % 27, c = (e/27) & 255, k = e/(27*256);
      off_wt[e] = offw[(((o<<8)+c)*9) + k];
    }
  } else if (blk < 4867) {                // style0 = zemb @ g0w.T + g0b (8x512)
    int e = (blk-4851)*256 + t; int b = e >> 9, j = e & 511;
    float s = g0b[j];
    const float* z = zemb + b*256; const float* w = g0w + j*256;
    for (int i = 0; i < 256; ++i) s += z[i]*w[i];
    style0[e] = s;
  } else if (blk < 4883) {                // style1
    int e = (blk-4867)*256 + t; int b = e >> 9, j = e & 511;
    float s = g1b[j];
    const float* z = zemb + b*256; const float* w = g1w + j*256;
    for (int i = 0; i < 256; ++i) s += z[i]*w[i];
    style1[e] = s;
  } else {                                // tproj = silu(temb) @ d0w.T + d0b (8x256)
    int e = (blk-4883)*256 + t; int b = e >> 8, o = e & 255;
    float s = d0b[o];
    const float* tb = temb + b*512; const float* w = d0w + o*512;
    for (int i = 0; i < 512; ++i) s += silu_f(tb[i])*w[i];
    tproj[e] = s;
  }
}

// ---------- reductions ----------
__device__ __forceinline__ void block_reduce2(float& s, float& q){
  for (int off = 32; off > 0; off >>= 1) {
    s += __shfl_down(s, off, 64);
    q += __shfl_down(q, off, 64);
  }
  __shared__ float ss[4], qs[4];
  int wid = threadIdx.x >> 6, lane = threadIdx.x & 63;
  if (lane == 0) { ss[wid] = s; qs[wid] = q; }
  __syncthreads();
  if (threadIdx.x == 0) { s = ss[0]+ss[1]+ss[2]+ss[3]; q = qs[0]+qs[1]+qs[2]+qs[3]; }
}

__global__ __launch_bounds__(256) void gn0_stats_kernel(
    const float* __restrict__ x, float* __restrict__ mu, float* __restrict__ rs)
{
  int blk = blockIdx.x;  // b*32+g ; NCHW group = 32768 contiguous
  const float4* p4 = (const float4*)(x + (size_t)blk*32768);
  float s = 0.f, q = 0.f;
  for (int i = threadIdx.x; i < 8192; i += 256) {
    float4 v = p4[i];
    s += v.x+v.y+v.z+v.w;
    q += v.x*v.x + v.y*v.y + v.z*v.z + v.w*v.w;
  }
  block_reduce2(s, q);
  if (threadIdx.x == 0) {
    float m = s * (1.f/32768.f);
    float var = q * (1.f/32768.f) - m*m;
    mu[blk] = m; rs[blk] = rsqrtf(var + EPSV);
  }
}

__global__ __launch_bounds__(256) void gn1_stats_kernel(
    const float* __restrict__ h1, float* __restrict__ mu, float* __restrict__ rs)
{
  int blk = blockIdx.x;  // b*32+g over NHWC
  int b = blk >> 5, g = blk & 31;
  const float* base = h1 + (size_t)b*1048576 + g*8;
  float s = 0.f, q = 0.f;
  for (int i = threadIdx.x; i < 16384; i += 256) {
    float2 v = *(const float2*)(base + (size_t)(i>>2)*256 + ((i&3)<<1));
    s += v.x+v.y; q += v.x*v.x + v.y*v.y;
  }
  block_reduce2(s, q);
  if (threadIdx.x == 0) {
    float m = s * (1.f/32768.f);
    float var = q * (1.f/32768.f) - m*m;
    mu[blk] = m; rs[blk] = rsqrtf(var + EPSV);
  }
}

// ---------- h0 = silu(adagn(x)) NCHW -> NHWC fp32 ----------
__global__ __launch_bounds__(256) void h0_kernel(
    const float* __restrict__ x, const float* __restrict__ style0,
    const float* __restrict__ mu, const float* __restrict__ rs,
    float* __restrict__ h0)
{
  int blk = blockIdx.x;          // b(8) x ptile(64) x ctile(8)
  int b  = blk >> 9;
  int pt = (blk >> 3) & 63;
  int ct = blk & 7;
  __shared__ float tile[32][65];
  int p0 = pt*64, c0 = ct*32;
  int t = threadIdx.x;
  for (int it = 0; it < 8; ++it) {
    int c = c0 + it*4 + (t >> 6);
    int p = p0 + (t & 63);
    float v = x[((size_t)(b*256 + c))*4096 + p];
    int g = c >> 3;
    float m  = mu[b*32+g], r = rs[b*32+g];
    float ga = style0[b*512 + c], be = style0[b*512 + 256 + c];
    float u = ga * (v - m) * r + be;
    tile[c - c0][p - p0] = silu_f(u);
  }
  __syncthreads();
  for (int it = 0; it < 8; ++it) {
    int pp = it*8 + (t >> 5);
    int cc = t & 31;
    h0[((size_t)(b*4096 + p0 + pp))*256 + c0 + cc] = tile[cc][pp];
  }
}

// ---------- offset conv (27 outch, fp32) ----------
__global__ __launch_bounds__(256) void offset_conv_kernel(
    const float* __restrict__ h0, const float* __restrict__ off_wt,
    const float* __restrict__ off_b, float* __restrict__ off_t)
{
  int blk = blockIdx.x;          // b*64 + y
  int b = blk >> 6, y = blk & 63;
  for (int idx = threadIdx.x; idx < 1728; idx += 256) {
    int p = idx / 27, oc = idx % 27;
    float acc = off_b[oc];
    for (int k = 0; k < 9; ++k) {
      int yy = y + k/3 - 1, xx = p + k%3 - 1;
      if (yy < 0 || yy >= 64 || xx < 0 || xx >= 64) continue;
      const float4* hp4 = (const float4*)(h0 + ((size_t)(b*4096) + yy*64 + xx)*256);
      const float* wp = off_wt + k*256*27 + oc;
      #pragma unroll 4
      for (int c4 = 0; c4 < 64; ++c4) {
        float4 h4 = hp4[c4];
        acc += h4.x*wp[(c4*4+0)*27] + h4.y*wp[(c4*4+1)*27]
             + h4.z*wp[(c4*4+2)*27] + h4.w*wp[(c4*4+3)*27];
      }
    }
    off_t[((size_t)(b*4096) + y*64 + p)*27 + oc] = acc;
  }
}

// ---------- deformable conv, MFMA ----------
__global__ __launch_bounds__(256) void deform_mfma_kernel(
    const float* __restrict__ h0, const float* __restrict__ off_t,
    const unsigned short* __restrict__ wt, const float* __restrict__ dcn_b,
    const float* __restrict__ tproj, float* __restrict__ h1)
{
  int b  = blockIdx.x >> 7;
  int p0 = (blockIdx.x & 127) * 32;            // 32 px, same row (64%32==0)
  int t = threadIdx.x;
  int lane = t & 63, wv = t >> 6;
  int r = lane & 15, g = lane >> 4;

  __shared__ unsigned short samp[32*264];      // [px][264] bf16
  __shared__ int   iy0s[288], ix0s[288], iy1s[288], ix1s[288];
  __shared__ float w00s[288], w01s[288], w10s[288], w11s[288];

  for (int tp = t; tp < 288; tp += 256) {      // 32 px x 9 taps
    int i = tp / 9, k = tp - i*9;
    int p = p0 + i; int y = p >> 6, xq = p & 63;
    const float* ob = off_t + ((size_t)(b*4096) + p)*27;
    float dy = ob[2*k], dx = ob[2*k+1];
    float mask = 1.f / (1.f + __expf(-ob[18+k]));
    float py = dy + (float)(k/3 + y - 1);
    float px = dx + (float)(k%3 + xq - 1);
    float fy0 = floorf(py), fx0 = floorf(px);
    float wy1 = py - fy0, wx1 = px - fx0;
    int y0 = (int)fy0, x0 = (int)fx0, y1 = y0+1, x1 = x0+1;
    float vy0 = (y0 >= 0 && y0 < 64) ? 1.f : 0.f;
    float vy1 = (y1 >= 0 && y1 < 64) ? 1.f : 0.f;
    float vx0 = (x0 >= 0 && x0 < 64) ? 1.f : 0.f;
    float vx1 = (x1 >= 0 && x1 < 64) ? 1.f : 0.f;
    iy0s[tp] = min(max(y0,0),63); ix0s[tp] = min(max(x0,0),63);
    iy1s[tp] = min(max(y1,0),63); ix1s[tp] = min(max(x1,0),63);
    w00s[tp] = (1.f-wy1)*(1.f-wx1)*vy0*vx0*mask;
    w01s[tp] = (1.f-wy1)*wx1      *vy0*vx1*mask;
    w10s[tp] = wy1      *(1.f-wx1)*vy1*vx0*mask;
    w11s[tp] = wy1      *wx1      *vy1*vx1*mask;
  }
  __syncthreads();

  f32x4 zero4 = {0.f,0.f,0.f,0.f};
  f32x4 acc[2][4];
  #pragma unroll
  for (int m = 0; m < 2; ++m)
    #pragma unroll
    for (int n = 0; n < 4; ++n) acc[m][n] = zero4;

  const float* hb = h0 + (size_t)b*1048576;
  int mypx = t & 31, cbase = (t >> 5) * 32;    // gather: 32 px x (8 chunks of 32c)
  int o_lane = wv*64 + r;

  for (int k = 0; k < 9; ++k) {
    { // gather tap k -> samp bf16
      int tp = mypx*9 + k;
      const float* p00 = hb + ((size_t)iy0s[tp]*64 + ix0s[tp])*256 + cbase;
      const float* p01 = hb + ((size_t)iy0s[tp]*64 + ix1s[tp])*256 + cbase;
      const float* p10 = hb + ((size_t)iy1s[tp]*64 + ix0s[tp])*256 + cbase;
      const float* p11 = hb + ((size_t)iy1s[tp]*64 + ix1s[tp])*256 + cbase;
      float a00 = w00s[tp], a01 = w01s[tp], a10 = w10s[tp], a11 = w11s[tp];
      unsigned short* sp = &samp[mypx*264 + cbase];
      #pragma unroll
      for (int i = 0; i < 8; ++i) {
        float4 v00 = *(const float4*)(p00 + i*4);
        float4 v01 = *(const float4*)(p01 + i*4);
        float4 v10 = *(const float4*)(p10 + i*4);
        float4 v11 = *(const float4*)(p11 + i*4);
        float o0 = a00*v00.x + a01*v01.x + a10*v10.x + a11*v11.x;
        float o1 = a00*v00.y + a01*v01.y + a10*v10.y + a11*v11.y;
        float o2 = a00*v00.z + a01*v01.z + a10*v10.z + a11*v11.z;
        float o3 = a00*v00.w + a01*v01.w + a10*v10.w + a11*v11.w;
        ushort4 pk; pk.x = f2bf(o0); pk.y = f2bf(o1); pk.z = f2bf(o2); pk.w = f2bf(o3);
        *(ushort4*)(sp + i*4) = pk;
      }
    }
    __syncthreads();

    const unsigned short* wk = wt + (size_t)k*65536;   // [32][256][8] for this tap
    #pragma unroll
    for (int kc = 0; kc < 8; ++kc) {
      bf16x8 a0 = *(const bf16x8*)&samp[(     r)*264 + kc*32 + g*8];
      bf16x8 a1 = *(const bf16x8*)&samp[(16 + r)*264 + kc*32 + g*8];
      const unsigned short* wb = wk + (size_t)(kc*4 + g)*2048 + o_lane*8;
      bf16x8 b0 = *(const bf16x8*)&wb[  0*8];
      bf16x8 b1 = *(const bf16x8*)&wb[ 16*8];
      bf16x8 b2 = *(const bf16x8*)&wb[ 32*8];
      bf16x8 b3 = *(const bf16x8*)&wb[ 48*8];
      acc[0][0] = __builtin_amdgcn_mfma_f32_16x16x32_bf16(a0, b0, acc[0][0], 0, 0, 0);
      acc[0][1] = __builtin_amdgcn_mfma_f32_16x16x32_bf16(a0, b1, acc[0][1], 0, 0, 0);
      acc[0][2] = __builtin_amdgcn_mfma_f32_16x16x32_bf16(a0, b2, acc[0][2], 0, 0, 0);
      acc[0][3] = __builtin_amdgcn_mfma_f32_16x16x32_bf16(a0, b3, acc[0][3], 0, 0, 0);
      acc[1][0] = __builtin_amdgcn_mfma_f32_16x16x32_bf16(a1, b0, acc[1][0], 0, 0, 0);
      acc[1][1] = __builtin_amdgcn_mfma_f32_16x16x32_bf16(a1, b1, acc[1][1], 0, 0, 0);
      acc[1][2] = __builtin_amdgcn_mfma_f32_16x16x32_bf16(a1, b2, acc[1][2], 0, 0, 0);
      acc[1][3] = __builtin_amdgcn_mfma_f32_16x16x32_bf16(a1, b3, acc[1][3], 0, 0, 0);
    }
    __syncthreads();
  }

  #pragma unroll
  for (int n = 0; n < 4; ++n) {
    int o = o_lane + n*16;
    float bs = dcn_b[o] + tproj[b*256 + o];
    #pragma unroll
    for (int m = 0; m < 2; ++m)
      #pragma unroll
      for (int j = 0; j < 4; ++j) {
        int pxl = m*16 + g*4 + j;
        h1[((size_t)(b*4096) + p0 + pxl)*256 + o] = acc[m][n][j] + bs;
      }
  }
}

// ---------- h2 = silu(adagn(h1)) -> bf16 NHWC ----------
__global__ __launch_bounds__(256) void h2_bf16_kernel(
    const float* __restrict__ h1, const float* __restrict__ style1,
    const float* __restrict__ mu, const float* __restrict__ rs,
    unsigned short* __restrict__ h2b)
{
  size_t i = ((size_t)blockIdx.x*256 + threadIdx.x)*4;
  float4 v = *(const float4*)(h1 + i);
  int b = (int)(i >> 20);
  int c0 = (int)(i & 255);
  float vv[4] = {v.x, v.y, v.z, v.w};
  ushort4 pk;
  unsigned short* po = (unsigned short*)&pk;
  #pragma unroll
  for (int j = 0; j < 4; ++j) {
    int c = c0 + j, g = c >> 3;
    float m  = mu[b*32+g], r = rs[b*32+g];
    float ga = style1[b*512 + c], be = style1[b*512 + 256 + c];
    float u = ga * (vv[j] - m) * r + be;
    po[j] = f2bf(silu_f(u));
  }
  *(ushort4*)(h2b + i) = pk;
}

// ---------- conv1 3x3 MFMA + residual -> out NCHW ----------
__global__ __launch_bounds__(256) void conv1_mfma_kernel(
    const unsigned short* __restrict__ h2b, const unsigned short* __restrict__ wt,
    const float* __restrict__ c1_b, const float* __restrict__ x,
    float* __restrict__ out)
{
  int b  = blockIdx.x >> 7;
  int p0 = (blockIdx.x & 127) * 32;
  int y = p0 >> 6, xb = p0 & 63;
  int t = threadIdx.x;
  int lane = t & 63, wv = t >> 6;
  int r = lane & 15, g = lane >> 4;

  __shared__ unsigned short aw[3*34*264];      // rows y-1..y+1, px window xb-1..xb+32

  const unsigned short* h2base = h2b + (size_t)b*1048576;
  for (int idx = t; idx < 3264; idx += 256) {  // 3 rows * 34 px * 32 chunks(8c)
    int row = idx / 1088, rem = idx - row*1088;
    int px = rem >> 5, c8 = rem & 31;
    int yy = y + row - 1, xx = xb - 1 + px;
    bf16x8 v = {0,0,0,0,0,0,0,0};
    if (yy >= 0 && yy < 64 && xx >= 0 && xx < 64)
      v = *(const bf16x8*)&h2base[((size_t)yy*64 + xx)*256 + c8*8];
    *(bf16x8*)&aw[(row*34 + px)*264 + c8*8] = v;
  }
  __syncthreads();

  f32x4 zero4 = {0.f,0.f,0.f,0.f};
  f32x4 acc[2][4];
  #pragma unroll
  for (int m = 0; m < 2; ++m)
    #pragma unroll
    for (int n = 0; n < 4; ++n) acc[m][n] = zero4;

  int o_lane = wv*64 + r;
  for (int k = 0; k < 9; ++k) {
    int ky = k/3, kxo = k%3;                    // window idx = px_local + kxo
    const unsigned short* abase = &aw[(ky*34)*264];
    const unsigned short* wk = wt + (size_t)k*65536;
    #pragma unroll
    for (int kc = 0; kc < 8; ++kc) {
      bf16x8 a0 = *(const bf16x8*)&abase[(kxo +      r)*264 + kc*32 + g*8];
      bf16x8 a1 = *(const bf16x8*)&abase[(kxo + 16 + r)*264 + kc*32 + g*8];
      const unsigned short* wb = wk + (size_t)(kc*4 + g)*2048 + o_lane*8;
      bf16x8 b0 = *(const bf16x8*)&wb[  0*8];
      bf16x8 b1 = *(const bf16x8*)&wb[ 16*8];
      bf16x8 b2 = *(const bf16x8*)&wb[ 32*8];
      bf16x8 b3 = *(const bf16x8*)&wb[ 48*8];
      acc[0][0] = __builtin_amdgcn_mfma_f32_16x16x32_bf16(a0, b0, acc[0][0], 0, 0, 0);
      acc[0][1] = __builtin_amdgcn_mfma_f32_16x16x32_bf16(a0, b1, acc[0][1], 0, 0, 0);
      acc[0][2] = __builtin_amdgcn_mfma_f32_16x16x32_bf16(a0, b2, acc[0][2], 0, 0, 0);
      acc[0][3] = __builtin_amdgcn_mfma_f32_16x16x32_bf16(a0, b3, acc[0][3], 0, 0, 0);
      acc[1][0] = __builtin_amdgcn_mfma_f32_16x16x32_bf16(a1, b0, acc[1][0], 0, 0, 0);
      acc[1][1] = __builtin_amdgcn_mfma_f32_16x16x32_bf16(a1, b1, acc[1][1], 0, 0, 0);
      acc[1][2] = __builtin_amdgcn_mfma_f32_16x16x32_bf16(a1, b2, acc[1][2], 0, 0, 0);
      acc[1][3] = __builtin_amdgcn_mfma_f32_16x16x32_bf16(a1, b3, acc[1][3], 0, 0, 0);
    }
  }

  #pragma unroll
  for (int n = 0; n < 4; ++n) {
    int o = o_lane + n*16;
    float cb = c1_b[o];
    #pragma unroll
    for (int m = 0; m < 2; ++m)
      #pragma unroll
      for (int j = 0; j < 4; ++j) {
        int pxl = m*16 + g*4 + j;
        size_t oi = ((size_t)(b*256 + o))*4096 + p0 + pxl;
        out[oi] = x[oi] + acc[m][n][j] + cb;
      }
  }
}

extern "C" void kernel_launch(void* const* d_in, const int* in_sizes, int n_in,
                              void* d_out, int out_size, void* d_ws, size_t ws_size,
                              hipStream_t stream) {
  const float* x    = (const float*)d_in[0];
  const float* temb = (const float*)d_in[1];
  const float* zemb = (const float*)d_in[2];
  const float* g0w  = (const float*)d_in[3];
  const float* g0b  = (const float*)d_in[4];
  const float* offw = (const float*)d_in[5];
  const float* offb = (const float*)d_in[6];
  const float* dcnw = (const float*)d_in[7];
  const float* dcnb = (const float*)d_in[8];
  const float* d0w  = (const float*)d_in[9];
  const float* d0b  = (const float*)d_in[10];
  const float* g1w  = (const float*)d_in[11];
  const float* g1b  = (const float*)d_in[12];
  const float* c1w  = (const float*)d_in[13];
  const float* c1b  = (const float*)d_in[14];
  float* out = (float*)d_out;
  float* ws  = (float*)d_ws;

  float* h0      = ws + WS_H0;
  float* h1      = ws + WS_H1;
  float* off_t   = ws + WS_OFFT;
  unsigned short* wtd = (unsigned short*)(ws + WS_WTD);
  unsigned short* wtc = (unsigned short*)(ws + WS_WTC);
  float* off_wt  = ws + WS_OFFWT;
  float* style0  = ws + WS_STYLE0;
  float* style1  = ws + WS_STYLE1;
  float* tproj   = ws + WS_TPROJ;
  float* mu0     = ws + WS_MU0;
  float* rs0     = ws + WS_RS0;
  float* mu1     = ws + WS_MU1;
  float* rs1     = ws + WS_RS1;
  unsigned short* h2b = (unsigned short*)(ws + WS_H0);  // reuse h0 region (h0 dead after deform)

  prep_kernel<<<4891, 256, 0, stream>>>(zemb, temb, g0w, g0b, g1w, g1b, d0w, d0b,
                                        dcnw, c1w, offw, wtd, wtc, off_wt,
                                        style0, style1, tproj);
  gn0_stats_kernel<<<256, 256, 0, stream>>>(x, mu0, rs0);
  h0_kernel<<<4096, 256, 0, stream>>>(x, style0, mu0, rs0, h0);
  offset_conv_kernel<<<512, 256, 0, stream>>>(h0, off_wt, offb, off_t);
  deform_mfma_kernel<<<1024, 256, 0, stream>>>(h0, off_t, wtd, dcnb, tproj, h1);
  gn1_stats_kernel<<<256, 256, 0, stream>>>(h1, mu1, rs1);
  h2_bf16_kernel<<<8192, 256, 0, stream>>>(h1, style1, mu1, rs1, h2b);
  conv1_mfma_kernel<<<1024, 256, 0, stream>>>(h2b, wtc, c1b, x, out);
}

// Round 6
// 298.535 us; speedup vs baseline: 3.6674x; 3.6674x over previous
//
#include <hip/hip_runtime.h>
#include <hip/hip_bf16.h>

// ResnetBlockDDPMpp_Adagn: B=8, CIN=COUT=256, H=W=64, G=32, K=3
// Round 6: identical kernels to R5; ONLY fix = ws layout arithmetic.
//  - R5 bug: WS_WTC-WS_WTD=147456 floats but wtd needs 294912 floats
//    (589824 ushorts) -> wtc aliased wtd's top half and ran over offwtb/
//    style0/style1/tproj (all written concurrently inside prep_kernel ->
//    race -> corrupted styles/weights -> GN var<0 -> rsqrt NaN).
//  - R4 layout had correct 294912 spacing; restored here.

#define EPSV 1e-6f

typedef short  bf16x8 __attribute__((ext_vector_type(8)));
typedef float  f32x4  __attribute__((ext_vector_type(4)));

__device__ __forceinline__ float silu_f(float v){ return v / (1.f + __expf(-v)); }
__device__ __forceinline__ unsigned short f2bf(float f){
  unsigned int u = __float_as_uint(f);
  u = (u + 0x7FFFu + ((u >> 16) & 1u)) >> 16;
  return (unsigned short)u;
}
__device__ __forceinline__ float bf2f(unsigned short u){
  return __uint_as_float(((unsigned int)u) << 16);
}

// ---------------- ws layout (float units) ----------------
#define WS_H0B     0            // 8*4096*256 bf16 = 4194304 floats; reused as h2 bf16
#define WS_H1      4194304      // 8*4096*256 fp32
#define WS_OFFT    12582912     // 8*4096*27 fp32 = 884736
#define WS_WTD     13467648     // dcn bf16 589824 ushort = 294912 floats
#define WS_WTC     13762560     // conv1 bf16 294912 floats
#define WS_OFFWTB  14057472     // offw bf16 [9][32][32][8] = 73728 ushort = 36864 floats
#define WS_STYLE0  14094336     // 8*512
#define WS_STYLE1  14098432     // 8*512
#define WS_TPROJ   14102528     // 8*256
#define WS_MU0     14104576
#define WS_RS0     14104832
#define WS_MU1     14105088
#define WS_RS1     14105344
// end 14,105,600 floats = 56.4 MB

// ---------- prep: weight packs + tiny GEMMs ----------
__global__ __launch_bounds__(256) void prep_kernel(
    const float* __restrict__ zemb, const float* __restrict__ temb,
    const float* __restrict__ g0w, const float* __restrict__ g0b,
    const float* __restrict__ g1w, const float* __restrict__ g1b,
    const float* __restrict__ d0w, const float* __restrict__ d0b,
    const float* __restrict__ dcn_w, const float* __restrict__ c1w,
    const float* __restrict__ offw,
    unsigned short* __restrict__ wtd, unsigned short* __restrict__ wtc,
    unsigned short* __restrict__ offwtb,
    float* __restrict__ style0, float* __restrict__ style1, float* __restrict__ tproj)
{
  int blk = blockIdx.x, t = threadIdx.x;
  if (blk < 2304) {                       // dcn pack: e=((k*32+c8)*256+o)*8+j
    int e = blk*256 + t;
    int j = e & 7, o = (e >> 3) & 255, c8 = (e >> 11) & 31, k = e >> 16;
    wtd[e] = f2bf(dcn_w[((o*256 + c8*8 + j)*9) + k]);
  } else if (blk < 4608) {                // conv1 pack
    int e = (blk-2304)*256 + t;
    int j = e & 7, o = (e >> 3) & 255, c8 = (e >> 11) & 31, k = e >> 16;
    wtc[e] = f2bf(c1w[((o*256 + c8*8 + j)*9) + k]);
  } else if (blk < 4896) {                // offw pack: [9][32 c8][32 o][8 j], oc>=27 -> 0
    int e = (blk-4608)*256 + t;           // 73728 elems
    int j = e & 7, o = (e >> 3) & 31, c8 = (e >> 8) & 31, k = e >> 13;
    int c = c8*8 + j;
    offwtb[e] = (o < 27) ? f2bf(offw[((o*256 + c)*9) + k]) : (unsigned short)0;
  } else if (blk < 4912) {                // style0 = zemb @ g0w.T + g0b (8x512)
    int e = (blk-4896)*256 + t; int b = e >> 9, j = e & 511;
    float s = g0b[j];
    const float* z = zemb + b*256; const float* w = g0w + j*256;
    for (int i = 0; i < 256; ++i) s += z[i]*w[i];
    style0[e] = s;
  } else if (blk < 4928) {                // style1
    int e = (blk-4912)*256 + t; int b = e >> 9, j = e & 511;
    float s = g1b[j];
    const float* z = zemb + b*256; const float* w = g1w + j*256;
    for (int i = 0; i < 256; ++i) s += z[i]*w[i];
    style1[e] = s;
  } else {                                // tproj = silu(temb) @ d0w.T + d0b (8x256)
    int e = (blk-4928)*256 + t; int b = e >> 8, o = e & 255;
    float s = d0b[o];
    const float* tb = temb + b*512; const float* w = d0w + o*512;
    for (int i = 0; i < 512; ++i) s += silu_f(tb[i])*w[i];
    tproj[e] = s;
  }
}

// ---------- reductions ----------
__device__ __forceinline__ void block_reduce2(float& s, float& q){
  for (int off = 32; off > 0; off >>= 1) {
    s += __shfl_down(s, off, 64);
    q += __shfl_down(q, off, 64);
  }
  __shared__ float ss[4], qs[4];
  int wid = threadIdx.x >> 6, lane = threadIdx.x & 63;
  if (lane == 0) { ss[wid] = s; qs[wid] = q; }
  __syncthreads();
  if (threadIdx.x == 0) { s = ss[0]+ss[1]+ss[2]+ss[3]; q = qs[0]+qs[1]+qs[2]+qs[3]; }
}

__global__ __launch_bounds__(256) void gn0_stats_kernel(
    const float* __restrict__ x, float* __restrict__ mu, float* __restrict__ rs)
{
  int blk = blockIdx.x;  // b*32+g ; NCHW group = 32768 contiguous
  const float4* p4 = (const float4*)(x + (size_t)blk*32768);
  float s = 0.f, q = 0.f;
  for (int i = threadIdx.x; i < 8192; i += 256) {
    float4 v = p4[i];
    s += v.x+v.y+v.z+v.w;
    q += v.x*v.x + v.y*v.y + v.z*v.z + v.w*v.w;
  }
  block_reduce2(s, q);
  if (threadIdx.x == 0) {
    float m = s * (1.f/32768.f);
    float var = q * (1.f/32768.f) - m*m;
    mu[blk] = m; rs[blk] = rsqrtf(var + EPSV);
  }
}

__global__ __launch_bounds__(256) void gn1_stats_kernel(
    const float* __restrict__ h1, float* __restrict__ mu, float* __restrict__ rs)
{
  int blk = blockIdx.x;  // b*32+g over NHWC
  int b = blk >> 5, g = blk & 31;
  const float* base = h1 + (size_t)b*1048576 + g*8;
  float s = 0.f, q = 0.f;
  for (int i = threadIdx.x; i < 16384; i += 256) {
    float2 v = *(const float2*)(base + (size_t)(i>>2)*256 + ((i&3)<<1));
    s += v.x+v.y; q += v.x*v.x + v.y*v.y;
  }
  block_reduce2(s, q);
  if (threadIdx.x == 0) {
    float m = s * (1.f/32768.f);
    float var = q * (1.f/32768.f) - m*m;
    mu[blk] = m; rs[blk] = rsqrtf(var + EPSV);
  }
}

// ---------- h0 = silu(adagn(x)) NCHW -> NHWC bf16 ----------
__global__ __launch_bounds__(256) void h0_kernel(
    const float* __restrict__ x, const float* __restrict__ style0,
    const float* __restrict__ mu, const float* __restrict__ rs,
    unsigned short* __restrict__ h0b)
{
  int blk = blockIdx.x;          // b(8) x ptile(64) x ctile(8)
  int b  = blk >> 9;
  int pt = (blk >> 3) & 63;
  int ct = blk & 7;
  __shared__ float tile[32][65];
  int p0 = pt*64, c0 = ct*32;
  int t = threadIdx.x;
  for (int it = 0; it < 8; ++it) {
    int c = c0 + it*4 + (t >> 6);
    int p = p0 + (t & 63);
    float v = x[((size_t)(b*256 + c))*4096 + p];
    int g = c >> 3;
    float m  = mu[b*32+g], r = rs[b*32+g];
    float ga = style0[b*512 + c], be = style0[b*512 + 256 + c];
    float u = ga * (v - m) * r + be;
    tile[c - c0][p - p0] = silu_f(u);
  }
  __syncthreads();
  for (int it = 0; it < 8; ++it) {
    int pp = it*8 + (t >> 5);
    int cc = t & 31;
    h0b[((size_t)(b*4096 + p0 + pp))*256 + c0 + cc] = f2bf(tile[cc][pp]);
  }
}

// ---------- offset conv MFMA: 32 px x 32 oc (27 used), K=2304 ----------
__global__ __launch_bounds__(256) void offset_mfma_kernel(
    const unsigned short* __restrict__ h0b, const unsigned short* __restrict__ wt,
    const float* __restrict__ off_b, float* __restrict__ off_t)
{
  int b  = blockIdx.x >> 7;
  int p0 = (blockIdx.x & 127) * 32;
  int y = p0 >> 6, xb = p0 & 63;
  int t = threadIdx.x;
  int lane = t & 63, wv = t >> 6;
  int r = lane & 15, g = lane >> 4;

  __shared__ unsigned short aw[3*34*264];      // rows y-1..y+1, px xb-1..xb+32

  const unsigned short* hbase = h0b + (size_t)b*1048576;
  for (int idx = t; idx < 3264; idx += 256) {
    int row = idx / 1088, rem = idx - row*1088;
    int px = rem >> 5, c8 = rem & 31;
    int yy = y + row - 1, xx = xb - 1 + px;
    bf16x8 v = {0,0,0,0,0,0,0,0};
    if (yy >= 0 && yy < 64 && xx >= 0 && xx < 64)
      v = *(const bf16x8*)&hbase[((size_t)yy*64 + xx)*256 + c8*8];
    *(bf16x8*)&aw[(row*34 + px)*264 + c8*8] = v;
  }
  __syncthreads();

  int m = wv & 1, n = wv >> 1;                 // wave -> (px half, oc half)
  f32x4 acc = {0.f,0.f,0.f,0.f};
  for (int k = 0; k < 9; ++k) {
    int ky = k/3, kxo = k%3;
    const unsigned short* abase = &aw[(ky*34)*264];
    const unsigned short* wk = wt + (size_t)k*8192;   // [32 c8][32 o][8]
    #pragma unroll
    for (int kc = 0; kc < 8; ++kc) {
      bf16x8 a = *(const bf16x8*)&abase[(kxo + m*16 + r)*264 + kc*32 + g*8];
      bf16x8 bf = *(const bf16x8*)&wk[(size_t)((kc*4 + g)*32 + n*16 + r)*8];
      acc = __builtin_amdgcn_mfma_f32_16x16x32_bf16(a, bf, acc, 0, 0, 0);
    }
  }

  int oc = n*16 + r;
  if (oc < 27) {
    float bs = off_b[oc];
    #pragma unroll
    for (int j = 0; j < 4; ++j) {
      int px = m*16 + g*4 + j;
      off_t[((size_t)(b*4096) + p0 + px)*27 + oc] = acc[j] + bs;
    }
  }
}

// ---------- deformable conv, MFMA (h0 bf16) ----------
__global__ __launch_bounds__(256) void deform_mfma_kernel(
    const unsigned short* __restrict__ h0b, const float* __restrict__ off_t,
    const unsigned short* __restrict__ wt, const float* __restrict__ dcn_b,
    const float* __restrict__ tproj, float* __restrict__ h1)
{
  int b  = blockIdx.x >> 7;
  int p0 = (blockIdx.x & 127) * 32;            // 32 px, same row
  int t = threadIdx.x;
  int lane = t & 63, wv = t >> 6;
  int r = lane & 15, g = lane >> 4;

  __shared__ unsigned short samp[32*264];      // [px][264] bf16
  __shared__ int   iy0s[288], ix0s[288], iy1s[288], ix1s[288];
  __shared__ float w00s[288], w01s[288], w10s[288], w11s[288];

  for (int tp = t; tp < 288; tp += 256) {      // 32 px x 9 taps
    int i = tp / 9, k = tp - i*9;
    int p = p0 + i; int y = p >> 6, xq = p & 63;
    const float* ob = off_t + ((size_t)(b*4096) + p)*27;
    float dy = ob[2*k], dx = ob[2*k+1];
    float mask = 1.f / (1.f + __expf(-ob[18+k]));
    float py = dy + (float)(k/3 + y - 1);
    float px = dx + (float)(k%3 + xq - 1);
    float fy0 = floorf(py), fx0 = floorf(px);
    float wy1 = py - fy0, wx1 = px - fx0;
    int y0 = (int)fy0, x0 = (int)fx0, y1 = y0+1, x1 = x0+1;
    float vy0 = (y0 >= 0 && y0 < 64) ? 1.f : 0.f;
    float vy1 = (y1 >= 0 && y1 < 64) ? 1.f : 0.f;
    float vx0 = (x0 >= 0 && x0 < 64) ? 1.f : 0.f;
    float vx1 = (x1 >= 0 && x1 < 64) ? 1.f : 0.f;
    iy0s[tp] = min(max(y0,0),63); ix0s[tp] = min(max(x0,0),63);
    iy1s[tp] = min(max(y1,0),63); ix1s[tp] = min(max(x1,0),63);
    w00s[tp] = (1.f-wy1)*(1.f-wx1)*vy0*vx0*mask;
    w01s[tp] = (1.f-wy1)*wx1      *vy0*vx1*mask;
    w10s[tp] = wy1      *(1.f-wx1)*vy1*vx0*mask;
    w11s[tp] = wy1      *wx1      *vy1*vx1*mask;
  }
  __syncthreads();

  f32x4 zero4 = {0.f,0.f,0.f,0.f};
  f32x4 acc[2][4];
  #pragma unroll
  for (int m = 0; m < 2; ++m)
    #pragma unroll
    for (int n = 0; n < 4; ++n) acc[m][n] = zero4;

  const unsigned short* hb = h0b + (size_t)b*1048576;
  int mypx = t & 31, cbase = (t >> 5) * 32;    // gather: 32 px x (8 chunks of 32c)
  int o_lane = wv*64 + r;

  for (int k = 0; k < 9; ++k) {
    { // gather tap k -> samp bf16
      int tp = mypx*9 + k;
      const unsigned short* p00 = hb + ((size_t)iy0s[tp]*64 + ix0s[tp])*256 + cbase;
      const unsigned short* p01 = hb + ((size_t)iy0s[tp]*64 + ix1s[tp])*256 + cbase;
      const unsigned short* p10 = hb + ((size_t)iy1s[tp]*64 + ix0s[tp])*256 + cbase;
      const unsigned short* p11 = hb + ((size_t)iy1s[tp]*64 + ix1s[tp])*256 + cbase;
      float a00 = w00s[tp], a01 = w01s[tp], a10 = w10s[tp], a11 = w11s[tp];
      unsigned short* sp = &samp[mypx*264 + cbase];
      #pragma unroll
      for (int i = 0; i < 8; ++i) {
        ushort4 u00 = *(const ushort4*)(p00 + i*4);
        ushort4 u01 = *(const ushort4*)(p01 + i*4);
        ushort4 u10 = *(const ushort4*)(p10 + i*4);
        ushort4 u11 = *(const ushort4*)(p11 + i*4);
        float o0 = a00*bf2f(u00.x) + a01*bf2f(u01.x) + a10*bf2f(u10.x) + a11*bf2f(u11.x);
        float o1 = a00*bf2f(u00.y) + a01*bf2f(u01.y) + a10*bf2f(u10.y) + a11*bf2f(u11.y);
        float o2 = a00*bf2f(u00.z) + a01*bf2f(u01.z) + a10*bf2f(u10.z) + a11*bf2f(u11.z);
        float o3 = a00*bf2f(u00.w) + a01*bf2f(u01.w) + a10*bf2f(u10.w) + a11*bf2f(u11.w);
        ushort4 pk; pk.x = f2bf(o0); pk.y = f2bf(o1); pk.z = f2bf(o2); pk.w = f2bf(o3);
        *(ushort4*)(sp + i*4) = pk;
      }
    }
    __syncthreads();

    const unsigned short* wk = wt + (size_t)k*65536;   // [32][256][8] this tap
    #pragma unroll
    for (int kc = 0; kc < 8; ++kc) {
      bf16x8 a0 = *(const bf16x8*)&samp[(     r)*264 + kc*32 + g*8];
      bf16x8 a1 = *(const bf16x8*)&samp[(16 + r)*264 + kc*32 + g*8];
      const unsigned short* wb = wk + (size_t)(kc*4 + g)*2048 + o_lane*8;
      bf16x8 b0 = *(const bf16x8*)&wb[  0*8];
      bf16x8 b1 = *(const bf16x8*)&wb[ 16*8];
      bf16x8 b2 = *(const bf16x8*)&wb[ 32*8];
      bf16x8 b3 = *(const bf16x8*)&wb[ 48*8];
      acc[0][0] = __builtin_amdgcn_mfma_f32_16x16x32_bf16(a0, b0, acc[0][0], 0, 0, 0);
      acc[0][1] = __builtin_amdgcn_mfma_f32_16x16x32_bf16(a0, b1, acc[0][1], 0, 0, 0);
      acc[0][2] = __builtin_amdgcn_mfma_f32_16x16x32_bf16(a0, b2, acc[0][2], 0, 0, 0);
      acc[0][3] = __builtin_amdgcn_mfma_f32_16x16x32_bf16(a0, b3, acc[0][3], 0, 0, 0);
      acc[1][0] = __builtin_amdgcn_mfma_f32_16x16x32_bf16(a1, b0, acc[1][0], 0, 0, 0);
      acc[1][1] = __builtin_amdgcn_mfma_f32_16x16x32_bf16(a1, b1, acc[1][1], 0, 0, 0);
      acc[1][2] = __builtin_amdgcn_mfma_f32_16x16x32_bf16(a1, b2, acc[1][2], 0, 0, 0);
      acc[1][3] = __builtin_amdgcn_mfma_f32_16x16x32_bf16(a1, b3, acc[1][3], 0, 0, 0);
    }
    __syncthreads();
  }

  #pragma unroll
  for (int n = 0; n < 4; ++n) {
    int o = o_lane + n*16;
    float bs = dcn_b[o] + tproj[b*256 + o];
    #pragma unroll
    for (int m = 0; m < 2; ++m)
      #pragma unroll
      for (int j = 0; j < 4; ++j) {
        int pxl = m*16 + g*4 + j;
        h1[((size_t)(b*4096) + p0 + pxl)*256 + o] = acc[m][n][j] + bs;
      }
  }
}

// ---------- h2 = silu(adagn(h1)) -> bf16 NHWC ----------
__global__ __launch_bounds__(256) void h2_bf16_kernel(
    const float* __restrict__ h1, const float* __restrict__ style1,
    const float* __restrict__ mu, const float* __restrict__ rs,
    unsigned short* __restrict__ h2b)
{
  size_t i = ((size_t)blockIdx.x*256 + threadIdx.x)*4;
  float4 v = *(const float4*)(h1 + i);
  int b = (int)(i >> 20);
  int c0 = (int)(i & 255);
  float vv[4] = {v.x, v.y, v.z, v.w};
  ushort4 pk;
  unsigned short* po = (unsigned short*)&pk;
  #pragma unroll
  for (int j = 0; j < 4; ++j) {
    int c = c0 + j, g = c >> 3;
    float m  = mu[b*32+g], r = rs[b*32+g];
    float ga = style1[b*512 + c], be = style1[b*512 + 256 + c];
    float u = ga * (vv[j] - m) * r + be;
    po[j] = f2bf(silu_f(u));
  }
  *(ushort4*)(h2b + i) = pk;
}

// ---------- conv1 3x3 MFMA + residual -> out NCHW ----------
__global__ __launch_bounds__(256) void conv1_mfma_kernel(
    const unsigned short* __restrict__ h2b, const unsigned short* __restrict__ wt,
    const float* __restrict__ c1_b, const float* __restrict__ x,
    float* __restrict__ out)
{
  int b  = blockIdx.x >> 7;
  int p0 = (blockIdx.x & 127) * 32;
  int y = p0 >> 6, xb = p0 & 63;
  int t = threadIdx.x;
  int lane = t & 63, wv = t >> 6;
  int r = lane & 15, g = lane >> 4;

  __shared__ unsigned short aw[3*34*264];

  const unsigned short* h2base = h2b + (size_t)b*1048576;
  for (int idx = t; idx < 3264; idx += 256) {
    int row = idx / 1088, rem = idx - row*1088;
    int px = rem >> 5, c8 = rem & 31;
    int yy = y + row - 1, xx = xb - 1 + px;
    bf16x8 v = {0,0,0,0,0,0,0,0};
    if (yy >= 0 && yy < 64 && xx >= 0 && xx < 64)
      v = *(const bf16x8*)&h2base[((size_t)yy*64 + xx)*256 + c8*8];
    *(bf16x8*)&aw[(row*34 + px)*264 + c8*8] = v;
  }
  __syncthreads();

  f32x4 zero4 = {0.f,0.f,0.f,0.f};
  f32x4 acc[2][4];
  #pragma unroll
  for (int m = 0; m < 2; ++m)
    #pragma unroll
    for (int n = 0; n < 4; ++n) acc[m][n] = zero4;

  int o_lane = wv*64 + r;
  for (int k = 0; k < 9; ++k) {
    int ky = k/3, kxo = k%3;
    const unsigned short* abase = &aw[(ky*34)*264];
    const unsigned short* wk = wt + (size_t)k*65536;
    #pragma unroll
    for (int kc = 0; kc < 8; ++kc) {
      bf16x8 a0 = *(const bf16x8*)&abase[(kxo +      r)*264 + kc*32 + g*8];
      bf16x8 a1 = *(const bf16x8*)&abase[(kxo + 16 + r)*264 + kc*32 + g*8];
      const unsigned short* wb = wk + (size_t)(kc*4 + g)*2048 + o_lane*8;
      bf16x8 b0 = *(const bf16x8*)&wb[  0*8];
      bf16x8 b1 = *(const bf16x8*)&wb[ 16*8];
      bf16x8 b2 = *(const bf16x8*)&wb[ 32*8];
      bf16x8 b3 = *(const bf16x8*)&wb[ 48*8];
      acc[0][0] = __builtin_amdgcn_mfma_f32_16x16x32_bf16(a0, b0, acc[0][0], 0, 0, 0);
      acc[0][1] = __builtin_amdgcn_mfma_f32_16x16x32_bf16(a0, b1, acc[0][1], 0, 0, 0);
      acc[0][2] = __builtin_amdgcn_mfma_f32_16x16x32_bf16(a0, b2, acc[0][2], 0, 0, 0);
      acc[0][3] = __builtin_amdgcn_mfma_f32_16x16x32_bf16(a0, b3, acc[0][3], 0, 0, 0);
      acc[1][0] = __builtin_amdgcn_mfma_f32_16x16x32_bf16(a1, b0, acc[1][0], 0, 0, 0);
      acc[1][1] = __builtin_amdgcn_mfma_f32_16x16x32_bf16(a1, b1, acc[1][1], 0, 0, 0);
      acc[1][2] = __builtin_amdgcn_mfma_f32_16x16x32_bf16(a1, b2, acc[1][2], 0, 0, 0);
      acc[1][3] = __builtin_amdgcn_mfma_f32_16x16x32_bf16(a1, b3, acc[1][3], 0, 0, 0);
    }
  }

  #pragma unroll
  for (int n = 0; n < 4; ++n) {
    int o = o_lane + n*16;
    float cb = c1_b[o];
    #pragma unroll
    for (int m = 0; m < 2; ++m)
      #pragma unroll
      for (int j = 0; j < 4; ++j) {
        int pxl = m*16 + g*4 + j;
        size_t oi = ((size_t)(b*256 + o))*4096 + p0 + pxl;
        out[oi] = x[oi] + acc[m][n][j] + cb;
      }
  }
}

extern "C" void kernel_launch(void* const* d_in, const int* in_sizes, int n_in,
                              void* d_out, int out_size, void* d_ws, size_t ws_size,
                              hipStream_t stream) {
  const float* x    = (const float*)d_in[0];
  const float* temb = (const float*)d_in[1];
  const float* zemb = (const float*)d_in[2];
  const float* g0w  = (const float*)d_in[3];
  const float* g0b  = (const float*)d_in[4];
  const float* offw = (const float*)d_in[5];
  const float* offb = (const float*)d_in[6];
  const float* dcnw = (const float*)d_in[7];
  const float* dcnb = (const float*)d_in[8];
  const float* d0w  = (const float*)d_in[9];
  const float* d0b  = (const float*)d_in[10];
  const float* g1w  = (const float*)d_in[11];
  const float* g1b  = (const float*)d_in[12];
  const float* c1w  = (const float*)d_in[13];
  const float* c1b  = (const float*)d_in[14];
  float* out = (float*)d_out;
  float* ws  = (float*)d_ws;

  unsigned short* h0b = (unsigned short*)(ws + WS_H0B);
  float* h1      = ws + WS_H1;
  float* off_t   = ws + WS_OFFT;
  unsigned short* wtd  = (unsigned short*)(ws + WS_WTD);
  unsigned short* wtc  = (unsigned short*)(ws + WS_WTC);
  unsigned short* owtb = (unsigned short*)(ws + WS_OFFWTB);
  float* style0  = ws + WS_STYLE0;
  float* style1  = ws + WS_STYLE1;
  float* tproj   = ws + WS_TPROJ;
  float* mu0     = ws + WS_MU0;
  float* rs0     = ws + WS_RS0;
  float* mu1     = ws + WS_MU1;
  float* rs1     = ws + WS_RS1;
  unsigned short* h2b = (unsigned short*)(ws + WS_H0B);  // reuse (h0 dead after deform)

  prep_kernel<<<4936, 256, 0, stream>>>(zemb, temb, g0w, g0b, g1w, g1b, d0w, d0b,
                                        dcnw, c1w, offw, wtd, wtc, owtb,
                                        style0, style1, tproj);
  gn0_stats_kernel<<<256, 256, 0, stream>>>(x, mu0, rs0);
  h0_kernel<<<4096, 256, 0, stream>>>(x, style0, mu0, rs0, h0b);
  offset_mfma_kernel<<<1024, 256, 0, stream>>>(h0b, owtb, offb, off_t);
  deform_mfma_kernel<<<1024, 256, 0, stream>>>(h0b, off_t, wtd, dcnb, tproj, h1);
  gn1_stats_kernel<<<256, 256, 0, stream>>>(h1, mu1, rs1);
  h2_bf16_kernel<<<8192, 256, 0, stream>>>(h1, style1, mu1, rs1, h2b);
  conv1_mfma_kernel<<<1024, 256, 0, stream>>>(h2b, wtc, c1b, x, out);
}

// Round 7
// 290.013 us; speedup vs baseline: 3.7751x; 1.0294x over previous
//
#include <hip/hip_runtime.h>
#include <hip/hip_bf16.h>

// ResnetBlockDDPMpp_Adagn: B=8, CIN=COUT=256, H=W=64, G=32, K=3
// Round 7 (on R6 pass, 298us):
//  - R6 profile: deform 118us, MfmaUtil 13.5%, FETCH 168MB (h0b=16MB -> every
//    XCD refetched all batches: blockIdx>>7 batch decode defeats L2).
//  - Fix 1 (T1): XCD swizzle b=bid&7 on offset/deform/conv1 -> one batch per
//    XCD, h0b/h2b slice (2MB) L2-resident.
//  - Fix 2 (T14): deform gather remapped to 8 thr/px x 32 contiguous ch and
//    global loads for tap k+1 issued before MFMA of tap k (reg prefetch).

#define EPSV 1e-6f

typedef short  bf16x8 __attribute__((ext_vector_type(8)));
typedef float  f32x4  __attribute__((ext_vector_type(4)));

__device__ __forceinline__ float silu_f(float v){ return v / (1.f + __expf(-v)); }
__device__ __forceinline__ unsigned short f2bf(float f){
  unsigned int u = __float_as_uint(f);
  u = (u + 0x7FFFu + ((u >> 16) & 1u)) >> 16;
  return (unsigned short)u;
}
__device__ __forceinline__ float bf2f(unsigned short u){
  return __uint_as_float(((unsigned int)u) << 16);
}

// ---------------- ws layout (float units) ----------------
#define WS_H0B     0            // 8*4096*256 bf16 = 4194304 floats; reused as h2 bf16
#define WS_H1      4194304      // 8*4096*256 fp32
#define WS_OFFT    12582912     // 8*4096*27 fp32 = 884736
#define WS_WTD     13467648     // dcn bf16 589824 ushort = 294912 floats
#define WS_WTC     13762560     // conv1 bf16 294912 floats
#define WS_OFFWTB  14057472     // offw bf16 73728 ushort = 36864 floats
#define WS_STYLE0  14094336     // 8*512
#define WS_STYLE1  14098432     // 8*512
#define WS_TPROJ   14102528     // 8*256
#define WS_MU0     14104576
#define WS_RS0     14104832
#define WS_MU1     14105088
#define WS_RS1     14105344
// end 14,105,600 floats = 56.4 MB

// ---------- prep: weight packs + tiny GEMMs ----------
__global__ __launch_bounds__(256) void prep_kernel(
    const float* __restrict__ zemb, const float* __restrict__ temb,
    const float* __restrict__ g0w, const float* __restrict__ g0b,
    const float* __restrict__ g1w, const float* __restrict__ g1b,
    const float* __restrict__ d0w, const float* __restrict__ d0b,
    const float* __restrict__ dcn_w, const float* __restrict__ c1w,
    const float* __restrict__ offw,
    unsigned short* __restrict__ wtd, unsigned short* __restrict__ wtc,
    unsigned short* __restrict__ offwtb,
    float* __restrict__ style0, float* __restrict__ style1, float* __restrict__ tproj)
{
  int blk = blockIdx.x, t = threadIdx.x;
  if (blk < 2304) {                       // dcn pack: e=((k*32+c8)*256+o)*8+j
    int e = blk*256 + t;
    int j = e & 7, o = (e >> 3) & 255, c8 = (e >> 11) & 31, k = e >> 16;
    wtd[e] = f2bf(dcn_w[((o*256 + c8*8 + j)*9) + k]);
  } else if (blk < 4608) {                // conv1 pack
    int e = (blk-2304)*256 + t;
    int j = e & 7, o = (e >> 3) & 255, c8 = (e >> 11) & 31, k = e >> 16;
    wtc[e] = f2bf(c1w[((o*256 + c8*8 + j)*9) + k]);
  } else if (blk < 4896) {                // offw pack: [9][32 c8][32 o][8 j], oc>=27 -> 0
    int e = (blk-4608)*256 + t;           // 73728 elems
    int j = e & 7, o = (e >> 3) & 31, c8 = (e >> 8) & 31, k = e >> 13;
    int c = c8*8 + j;
    offwtb[e] = (o < 27) ? f2bf(offw[((o*256 + c)*9) + k]) : (unsigned short)0;
  } else if (blk < 4912) {                // style0 = zemb @ g0w.T + g0b (8x512)
    int e = (blk-4896)*256 + t; int b = e >> 9, j = e & 511;
    float s = g0b[j];
    const float* z = zemb + b*256; const float* w = g0w + j*256;
    for (int i = 0; i < 256; ++i) s += z[i]*w[i];
    style0[e] = s;
  } else if (blk < 4928) {                // style1
    int e = (blk-4912)*256 + t; int b = e >> 9, j = e & 511;
    float s = g1b[j];
    const float* z = zemb + b*256; const float* w = g1w + j*256;
    for (int i = 0; i < 256; ++i) s += z[i]*w[i];
    style1[e] = s;
  } else {                                // tproj = silu(temb) @ d0w.T + d0b (8x256)
    int e = (blk-4928)*256 + t; int b = e >> 8, o = e & 255;
    float s = d0b[o];
    const float* tb = temb + b*512; const float* w = d0w + o*512;
    for (int i = 0; i < 512; ++i) s += silu_f(tb[i])*w[i];
    tproj[e] = s;
  }
}

// ---------- reductions ----------
__device__ __forceinline__ void block_reduce2(float& s, float& q){
  for (int off = 32; off > 0; off >>= 1) {
    s += __shfl_down(s, off, 64);
    q += __shfl_down(q, off, 64);
  }
  __shared__ float ss[4], qs[4];
  int wid = threadIdx.x >> 6, lane = threadIdx.x & 63;
  if (lane == 0) { ss[wid] = s; qs[wid] = q; }
  __syncthreads();
  if (threadIdx.x == 0) { s = ss[0]+ss[1]+ss[2]+ss[3]; q = qs[0]+qs[1]+qs[2]+qs[3]; }
}

__global__ __launch_bounds__(256) void gn0_stats_kernel(
    const float* __restrict__ x, float* __restrict__ mu, float* __restrict__ rs)
{
  int blk = blockIdx.x;  // b*32+g ; NCHW group = 32768 contiguous
  const float4* p4 = (const float4*)(x + (size_t)blk*32768);
  float s = 0.f, q = 0.f;
  for (int i = threadIdx.x; i < 8192; i += 256) {
    float4 v = p4[i];
    s += v.x+v.y+v.z+v.w;
    q += v.x*v.x + v.y*v.y + v.z*v.z + v.w*v.w;
  }
  block_reduce2(s, q);
  if (threadIdx.x == 0) {
    float m = s * (1.f/32768.f);
    float var = q * (1.f/32768.f) - m*m;
    mu[blk] = m; rs[blk] = rsqrtf(var + EPSV);
  }
}

__global__ __launch_bounds__(256) void gn1_stats_kernel(
    const float* __restrict__ h1, float* __restrict__ mu, float* __restrict__ rs)
{
  int blk = blockIdx.x;  // b*32+g over NHWC
  int b = blk >> 5, g = blk & 31;
  const float* base = h1 + (size_t)b*1048576 + g*8;
  float s = 0.f, q = 0.f;
  for (int i = threadIdx.x; i < 16384; i += 256) {
    float2 v = *(const float2*)(base + (size_t)(i>>2)*256 + ((i&3)<<1));
    s += v.x+v.y; q += v.x*v.x + v.y*v.y;
  }
  block_reduce2(s, q);
  if (threadIdx.x == 0) {
    float m = s * (1.f/32768.f);
    float var = q * (1.f/32768.f) - m*m;
    mu[blk] = m; rs[blk] = rsqrtf(var + EPSV);
  }
}

// ---------- h0 = silu(adagn(x)) NCHW -> NHWC bf16 ----------
__global__ __launch_bounds__(256) void h0_kernel(
    const float* __restrict__ x, const float* __restrict__ style0,
    const float* __restrict__ mu, const float* __restrict__ rs,
    unsigned short* __restrict__ h0b)
{
  int blk = blockIdx.x;          // b(8) x ptile(64) x ctile(8)
  int b  = blk >> 9;
  int pt = (blk >> 3) & 63;
  int ct = blk & 7;
  __shared__ float tile[32][65];
  int p0 = pt*64, c0 = ct*32;
  int t = threadIdx.x;
  for (int it = 0; it < 8; ++it) {
    int c = c0 + it*4 + (t >> 6);
    int p = p0 + (t & 63);
    float v = x[((size_t)(b*256 + c))*4096 + p];
    int g = c >> 3;
    float m  = mu[b*32+g], r = rs[b*32+g];
    float ga = style0[b*512 + c], be = style0[b*512 + 256 + c];
    float u = ga * (v - m) * r + be;
    tile[c - c0][p - p0] = silu_f(u);
  }
  __syncthreads();
  for (int it = 0; it < 8; ++it) {
    int pp = it*8 + (t >> 5);
    int cc = t & 31;
    h0b[((size_t)(b*4096 + p0 + pp))*256 + c0 + cc] = f2bf(tile[cc][pp]);
  }
}

// ---------- offset conv MFMA: 32 px x 32 oc (27 used), K=2304 ----------
__global__ __launch_bounds__(256) void offset_mfma_kernel(
    const unsigned short* __restrict__ h0b, const unsigned short* __restrict__ wt,
    const float* __restrict__ off_b, float* __restrict__ off_t)
{
  int bid = blockIdx.x;
  int b  = bid & 7;                            // XCD swizzle: batch = bid%8
  int p0 = (bid >> 3) * 32;
  int y = p0 >> 6, xb = p0 & 63;
  int t = threadIdx.x;
  int lane = t & 63, wv = t >> 6;
  int r = lane & 15, g = lane >> 4;

  __shared__ unsigned short aw[3*34*264];      // rows y-1..y+1, px xb-1..xb+32

  const unsigned short* hbase = h0b + (size_t)b*1048576;
  for (int idx = t; idx < 3264; idx += 256) {
    int row = idx / 1088, rem = idx - row*1088;
    int px = rem >> 5, c8 = rem & 31;
    int yy = y + row - 1, xx = xb - 1 + px;
    bf16x8 v = {0,0,0,0,0,0,0,0};
    if (yy >= 0 && yy < 64 && xx >= 0 && xx < 64)
      v = *(const bf16x8*)&hbase[((size_t)yy*64 + xx)*256 + c8*8];
    *(bf16x8*)&aw[(row*34 + px)*264 + c8*8] = v;
  }
  __syncthreads();

  int m = wv & 1, n = wv >> 1;                 // wave -> (px half, oc half)
  f32x4 acc = {0.f,0.f,0.f,0.f};
  for (int k = 0; k < 9; ++k) {
    int ky = k/3, kxo = k%3;
    const unsigned short* abase = &aw[(ky*34)*264];
    const unsigned short* wk = wt + (size_t)k*8192;   // [32 c8][32 o][8]
    #pragma unroll
    for (int kc = 0; kc < 8; ++kc) {
      bf16x8 a = *(const bf16x8*)&abase[(kxo + m*16 + r)*264 + kc*32 + g*8];
      bf16x8 bf = *(const bf16x8*)&wk[(size_t)((kc*4 + g)*32 + n*16 + r)*8];
      acc = __builtin_amdgcn_mfma_f32_16x16x32_bf16(a, bf, acc, 0, 0, 0);
    }
  }

  int oc = n*16 + r;
  if (oc < 27) {
    float bs = off_b[oc];
    #pragma unroll
    for (int j = 0; j < 4; ++j) {
      int px = m*16 + g*4 + j;
      off_t[((size_t)(b*4096) + p0 + px)*27 + oc] = acc[j] + bs;
    }
  }
}

// ---------- deformable conv, MFMA (h0 bf16), reg-prefetch pipeline ----------
__global__ __launch_bounds__(256) void deform_mfma_kernel(
    const unsigned short* __restrict__ h0b, const float* __restrict__ off_t,
    const unsigned short* __restrict__ wt, const float* __restrict__ dcn_b,
    const float* __restrict__ tproj, float* __restrict__ h1)
{
  int bid = blockIdx.x;
  int b  = bid & 7;                            // XCD swizzle: batch = bid%8
  int p0 = (bid >> 3) * 32;                    // 32 px, same row
  int t = threadIdx.x;
  int lane = t & 63, wv = t >> 6;
  int r = lane & 15, g = lane >> 4;

  __shared__ unsigned short samp[32*264];      // [px][264] bf16
  __shared__ int   iy0s[288], ix0s[288], iy1s[288], ix1s[288];
  __shared__ float w00s[288], w01s[288], w10s[288], w11s[288];

  for (int tp = t; tp < 288; tp += 256) {      // 32 px x 9 taps
    int i = tp / 9, k = tp - i*9;
    int p = p0 + i; int y = p >> 6, xq = p & 63;
    const float* ob = off_t + ((size_t)(b*4096) + p)*27;
    float dy = ob[2*k], dx = ob[2*k+1];
    float mask = 1.f / (1.f + __expf(-ob[18+k]));
    float py = dy + (float)(k/3 + y - 1);
    float px = dx + (float)(k%3 + xq - 1);
    float fy0 = floorf(py), fx0 = floorf(px);
    float wy1 = py - fy0, wx1 = px - fx0;
    int y0 = (int)fy0, x0 = (int)fx0, y1 = y0+1, x1 = x0+1;
    float vy0 = (y0 >= 0 && y0 < 64) ? 1.f : 0.f;
    float vy1 = (y1 >= 0 && y1 < 64) ? 1.f : 0.f;
    float vx0 = (x0 >= 0 && x0 < 64) ? 1.f : 0.f;
    float vx1 = (x1 >= 0 && x1 < 64) ? 1.f : 0.f;
    iy0s[tp] = min(max(y0,0),63); ix0s[tp] = min(max(x0,0),63);
    iy1s[tp] = min(max(y1,0),63); ix1s[tp] = min(max(x1,0),63);
    w00s[tp] = (1.f-wy1)*(1.f-wx1)*vy0*vx0*mask;
    w01s[tp] = (1.f-wy1)*wx1      *vy0*vx1*mask;
    w10s[tp] = wy1      *(1.f-wx1)*vy1*vx0*mask;
    w11s[tp] = wy1      *wx1      *vy1*vx1*mask;
  }
  __syncthreads();

  f32x4 zero4 = {0.f,0.f,0.f,0.f};
  f32x4 acc[2][4];
  #pragma unroll
  for (int m = 0; m < 2; ++m)
    #pragma unroll
    for (int n = 0; n < 4; ++n) acc[m][n] = zero4;

  const unsigned short* hb = h0b + (size_t)b*1048576;
  int px = t >> 3;                             // 8 threads per pixel
  int ci = (t & 7) * 32;                       // 32 contiguous channels each
  int o_lane = wv*64 + r;

  bf16x8 pre[16];                              // 4 corners x 32ch prefetch
  auto loadk = [&](int kk) {
    int tp = px*9 + kk;
    const bf16x8* q00 = (const bf16x8*)(hb + ((size_t)iy0s[tp]*64 + ix0s[tp])*256 + ci);
    const bf16x8* q01 = (const bf16x8*)(hb + ((size_t)iy0s[tp]*64 + ix1s[tp])*256 + ci);
    const bf16x8* q10 = (const bf16x8*)(hb + ((size_t)iy1s[tp]*64 + ix0s[tp])*256 + ci);
    const bf16x8* q11 = (const bf16x8*)(hb + ((size_t)iy1s[tp]*64 + ix1s[tp])*256 + ci);
    pre[0] = q00[0]; pre[1] = q00[1]; pre[2] = q00[2]; pre[3] = q00[3];
    pre[4] = q01[0]; pre[5] = q01[1]; pre[6] = q01[2]; pre[7] = q01[3];
    pre[8] = q10[0]; pre[9] = q10[1]; pre[10] = q10[2]; pre[11] = q10[3];
    pre[12] = q11[0]; pre[13] = q11[1]; pre[14] = q11[2]; pre[15] = q11[3];
  };

  loadk(0);
  for (int k = 0; k < 9; ++k) {
    { // cvt + weighted sum from prefetch regs -> LDS (samp free: post-barrier)
      int tp = px*9 + k;
      float a00 = w00s[tp], a01 = w01s[tp], a10 = w10s[tp], a11 = w11s[tp];
      unsigned short* sp = &samp[px*264 + ci];
      #pragma unroll
      for (int ch = 0; ch < 4; ++ch) {
        bf16x8 o;
        #pragma unroll
        for (int e = 0; e < 8; ++e) {
          float v = a00*bf2f((unsigned short)pre[ch][e])
                  + a01*bf2f((unsigned short)pre[4+ch][e])
                  + a10*bf2f((unsigned short)pre[8+ch][e])
                  + a11*bf2f((unsigned short)pre[12+ch][e]);
          o[e] = (short)f2bf(v);
        }
        *(bf16x8*)(sp + ch*8) = o;
      }
    }
    if (k < 8) loadk(k+1);                     // issue next-tap loads: hide under MFMA
    __syncthreads();

    const unsigned short* wk = wt + (size_t)k*65536;   // [32][256][8] this tap
    #pragma unroll
    for (int kc = 0; kc < 8; ++kc) {
      bf16x8 a0 = *(const bf16x8*)&samp[(     r)*264 + kc*32 + g*8];
      bf16x8 a1 = *(const bf16x8*)&samp[(16 + r)*264 + kc*32 + g*8];
      const unsigned short* wb = wk + (size_t)(kc*4 + g)*2048 + o_lane*8;
      bf16x8 b0 = *(const bf16x8*)&wb[  0*8];
      bf16x8 b1 = *(const bf16x8*)&wb[ 16*8];
      bf16x8 b2 = *(const bf16x8*)&wb[ 32*8];
      bf16x8 b3 = *(const bf16x8*)&wb[ 48*8];
      acc[0][0] = __builtin_amdgcn_mfma_f32_16x16x32_bf16(a0, b0, acc[0][0], 0, 0, 0);
      acc[0][1] = __builtin_amdgcn_mfma_f32_16x16x32_bf16(a0, b1, acc[0][1], 0, 0, 0);
      acc[0][2] = __builtin_amdgcn_mfma_f32_16x16x32_bf16(a0, b2, acc[0][2], 0, 0, 0);
      acc[0][3] = __builtin_amdgcn_mfma_f32_16x16x32_bf16(a0, b3, acc[0][3], 0, 0, 0);
      acc[1][0] = __builtin_amdgcn_mfma_f32_16x16x32_bf16(a1, b0, acc[1][0], 0, 0, 0);
      acc[1][1] = __builtin_amdgcn_mfma_f32_16x16x32_bf16(a1, b1, acc[1][1], 0, 0, 0);
      acc[1][2] = __builtin_amdgcn_mfma_f32_16x16x32_bf16(a1, b2, acc[1][2], 0, 0, 0);
      acc[1][3] = __builtin_amdgcn_mfma_f32_16x16x32_bf16(a1, b3, acc[1][3], 0, 0, 0);
    }
    __syncthreads();
  }

  #pragma unroll
  for (int n = 0; n < 4; ++n) {
    int o = o_lane + n*16;
    float bs = dcn_b[o] + tproj[b*256 + o];
    #pragma unroll
    for (int m = 0; m < 2; ++m)
      #pragma unroll
      for (int j = 0; j < 4; ++j) {
        int pxl = m*16 + g*4 + j;
        h1[((size_t)(b*4096) + p0 + pxl)*256 + o] = acc[m][n][j] + bs;
      }
  }
}

// ---------- h2 = silu(adagn(h1)) -> bf16 NHWC ----------
__global__ __launch_bounds__(256) void h2_bf16_kernel(
    const float* __restrict__ h1, const float* __restrict__ style1,
    const float* __restrict__ mu, const float* __restrict__ rs,
    unsigned short* __restrict__ h2b)
{
  size_t i = ((size_t)blockIdx.x*256 + threadIdx.x)*4;
  float4 v = *(const float4*)(h1 + i);
  int b = (int)(i >> 20);
  int c0 = (int)(i & 255);
  float vv[4] = {v.x, v.y, v.z, v.w};
  ushort4 pk;
  unsigned short* po = (unsigned short*)&pk;
  #pragma unroll
  for (int j = 0; j < 4; ++j) {
    int c = c0 + j, g = c >> 3;
    float m  = mu[b*32+g], r = rs[b*32+g];
    float ga = style1[b*512 + c], be = style1[b*512 + 256 + c];
    float u = ga * (vv[j] - m) * r + be;
    po[j] = f2bf(silu_f(u));
  }
  *(ushort4*)(h2b + i) = pk;
}

// ---------- conv1 3x3 MFMA + residual -> out NCHW ----------
__global__ __launch_bounds__(256) void conv1_mfma_kernel(
    const unsigned short* __restrict__ h2b, const unsigned short* __restrict__ wt,
    const float* __restrict__ c1_b, const float* __restrict__ x,
    float* __restrict__ out)
{
  int bid = blockIdx.x;
  int b  = bid & 7;                            // XCD swizzle: batch = bid%8
  int p0 = (bid >> 3) * 32;
  int y = p0 >> 6, xb = p0 & 63;
  int t = threadIdx.x;
  int lane = t & 63, wv = t >> 6;
  int r = lane & 15, g = lane >> 4;

  __shared__ unsigned short aw[3*34*264];

  const unsigned short* h2base = h2b + (size_t)b*1048576;
  for (int idx = t; idx < 3264; idx += 256) {
    int row = idx / 1088, rem = idx - row*1088;
    int px = rem >> 5, c8 = rem & 31;
    int yy = y + row - 1, xx = xb - 1 + px;
    bf16x8 v = {0,0,0,0,0,0,0,0};
    if (yy >= 0 && yy < 64 && xx >= 0 && xx < 64)
      v = *(const bf16x8*)&h2base[((size_t)yy*64 + xx)*256 + c8*8];
    *(bf16x8*)&aw[(row*34 + px)*264 + c8*8] = v;
  }
  __syncthreads();

  f32x4 zero4 = {0.f,0.f,0.f,0.f};
  f32x4 acc[2][4];
  #pragma unroll
  for (int m = 0; m < 2; ++m)
    #pragma unroll
    for (int n = 0; n < 4; ++n) acc[m][n] = zero4;

  int o_lane = wv*64 + r;
  for (int k = 0; k < 9; ++k) {
    int ky = k/3, kxo = k%3;
    const unsigned short* abase = &aw[(ky*34)*264];
    const unsigned short* wk = wt + (size_t)k*65536;
    #pragma unroll
    for (int kc = 0; kc < 8; ++kc) {
      bf16x8 a0 = *(const bf16x8*)&abase[(kxo +      r)*264 + kc*32 + g*8];
      bf16x8 a1 = *(const bf16x8*)&abase[(kxo + 16 + r)*264 + kc*32 + g*8];
      const unsigned short* wb = wk + (size_t)(kc*4 + g)*2048 + o_lane*8;
      bf16x8 b0 = *(const bf16x8*)&wb[  0*8];
      bf16x8 b1 = *(const bf16x8*)&wb[ 16*8];
      bf16x8 b2 = *(const bf16x8*)&wb[ 32*8];
      bf16x8 b3 = *(const bf16x8*)&wb[ 48*8];
      acc[0][0] = __builtin_amdgcn_mfma_f32_16x16x32_bf16(a0, b0, acc[0][0], 0, 0, 0);
      acc[0][1] = __builtin_amdgcn_mfma_f32_16x16x32_bf16(a0, b1, acc[0][1], 0, 0, 0);
      acc[0][2] = __builtin_amdgcn_mfma_f32_16x16x32_bf16(a0, b2, acc[0][2], 0, 0, 0);
      acc[0][3] = __builtin_amdgcn_mfma_f32_16x16x32_bf16(a0, b3, acc[0][3], 0, 0, 0);
      acc[1][0] = __builtin_amdgcn_mfma_f32_16x16x32_bf16(a1, b0, acc[1][0], 0, 0, 0);
      acc[1][1] = __builtin_amdgcn_mfma_f32_16x16x32_bf16(a1, b1, acc[1][1], 0, 0, 0);
      acc[1][2] = __builtin_amdgcn_mfma_f32_16x16x32_bf16(a1, b2, acc[1][2], 0, 0, 0);
      acc[1][3] = __builtin_amdgcn_mfma_f32_16x16x32_bf16(a1, b3, acc[1][3], 0, 0, 0);
    }
  }

  #pragma unroll
  for (int n = 0; n < 4; ++n) {
    int o = o_lane + n*16;
    float cb = c1_b[o];
    #pragma unroll
    for (int m = 0; m < 2; ++m)
      #pragma unroll
      for (int j = 0; j < 4; ++j) {
        int pxl = m*16 + g*4 + j;
        size_t oi = ((size_t)(b*256 + o))*4096 + p0 + pxl;
        out[oi] = x[oi] + acc[m][n][j] + cb;
      }
  }
}

extern "C" void kernel_launch(void* const* d_in, const int* in_sizes, int n_in,
                              void* d_out, int out_size, void* d_ws, size_t ws_size,
                              hipStream_t stream) {
  const float* x    = (const float*)d_in[0];
  const float* temb = (const float*)d_in[1];
  const float* zemb = (const float*)d_in[2];
  const float* g0w  = (const float*)d_in[3];
  const float* g0b  = (const float*)d_in[4];
  const float* offw = (const float*)d_in[5];
  const float* offb = (const float*)d_in[6];
  const float* dcnw = (const float*)d_in[7];
  const float* dcnb = (const float*)d_in[8];
  const float* d0w  = (const float*)d_in[9];
  const float* d0b  = (const float*)d_in[10];
  const float* g1w  = (const float*)d_in[11];
  const float* g1b  = (const float*)d_in[12];
  const float* c1w  = (const float*)d_in[13];
  const float* c1b  = (const float*)d_in[14];
  float* out = (float*)d_out;
  float* ws  = (float*)d_ws;

  unsigned short* h0b = (unsigned short*)(ws + WS_H0B);
  float* h1      = ws + WS_H1;
  float* off_t   = ws + WS_OFFT;
  unsigned short* wtd  = (unsigned short*)(ws + WS_WTD);
  unsigned short* wtc  = (unsigned short*)(ws + WS_WTC);
  unsigned short* owtb = (unsigned short*)(ws + WS_OFFWTB);
  float* style0  = ws + WS_STYLE0;
  float* style1  = ws + WS_STYLE1;
  float* tproj   = ws + WS_TPROJ;
  float* mu0     = ws + WS_MU0;
  float* rs0     = ws + WS_RS0;
  float* mu1     = ws + WS_MU1;
  float* rs1     = ws + WS_RS1;
  unsigned short* h2b = (unsigned short*)(ws + WS_H0B);  // reuse (h0 dead after deform)

  prep_kernel<<<4936, 256, 0, stream>>>(zemb, temb, g0w, g0b, g1w, g1b, d0w, d0b,
                                        dcnw, c1w, offw, wtd, wtc, owtb,
                                        style0, style1, tproj);
  gn0_stats_kernel<<<256, 256, 0, stream>>>(x, mu0, rs0);
  h0_kernel<<<4096, 256, 0, stream>>>(x, style0, mu0, rs0, h0b);
  offset_mfma_kernel<<<1024, 256, 0, stream>>>(h0b, owtb, offb, off_t);
  deform_mfma_kernel<<<1024, 256, 0, stream>>>(h0b, off_t, wtd, dcnb, tproj, h1);
  gn1_stats_kernel<<<256, 256, 0, stream>>>(h1, mu1, rs1);
  h2_bf16_kernel<<<8192, 256, 0, stream>>>(h1, style1, mu1, rs1, h2b);
  conv1_mfma_kernel<<<1024, 256, 0, stream>>>(h2b, wtc, c1b, x, out);
}

// Round 9
// 276.523 us; speedup vs baseline: 3.9593x; 1.0488x over previous
//
#include <hip/hip_runtime.h>
#include <hip/hip_bf16.h>

// ResnetBlockDDPMpp_Adagn: B=8, CIN=COUT=256, H=W=64, G=32, K=3
// Round 9: identical kernels to R8; ONLY fix = ws layout arithmetic.
//  - R8 bug: h1b (8*4096*256 bf16 = 4,194,304 float slots) was given
//    2,097,152 -> upper half overlaid off_t; deform wrote h1b while other
//    blocks read off_t -> garbage offsets -> py inf -> wy1 NaN.
//  - Dbuf pipeline verified safe: wave reaches write-buf(k&1)@k+2 only after
//    barrier(k+1), which requires all waves done with MFMA(k) on buf(k&1).

#define EPSV 1e-6f

typedef short  bf16x8 __attribute__((ext_vector_type(8)));
typedef float  f32x4  __attribute__((ext_vector_type(4)));

__device__ __forceinline__ float silu_f(float v){ return v / (1.f + __expf(-v)); }
__device__ __forceinline__ unsigned short f2bf(float f){
  unsigned int u = __float_as_uint(f);
  u = (u + 0x7FFFu + ((u >> 16) & 1u)) >> 16;
  return (unsigned short)u;
}
__device__ __forceinline__ float bf2f(unsigned short u){
  return __uint_as_float(((unsigned int)u) << 16);
}

// ---------------- ws layout (float units) ----------------
// region sizes (floats): h0b 4194304 | h1b 4194304 | offt 884736 | wtd 294912
//                        wtc 294912 | owtb 36864 | st0 4096 | st1 4096
//                        tproj 2048 | mu/rs 4x256
#define WS_H0B     0            // 8*4096*256 bf16 (reused as h2 bf16)
#define WS_H1B     4194304      // 8*4096*256 bf16
#define WS_OFFT    8388608      // 8*4096*27 fp32
#define WS_WTD     9273344      // dcn bf16 [9][32][256][8]
#define WS_WTC     9568256      // conv1 bf16 same
#define WS_OFFWTB  9863168      // offw bf16 [9][32][32][8]
#define WS_STYLE0  9900032
#define WS_STYLE1  9904128
#define WS_TPROJ   9908224
#define WS_MU0     9910272
#define WS_RS0     9910528
#define WS_MU1     9910784
#define WS_RS1     9911040
// end 9,911,296 floats = 39.6 MB

// ---------- prep: weight packs + tiny GEMMs ----------
__global__ __launch_bounds__(256) void prep_kernel(
    const float* __restrict__ zemb, const float* __restrict__ temb,
    const float* __restrict__ g0w, const float* __restrict__ g0b,
    const float* __restrict__ g1w, const float* __restrict__ g1b,
    const float* __restrict__ d0w, const float* __restrict__ d0b,
    const float* __restrict__ dcn_w, const float* __restrict__ c1w,
    const float* __restrict__ offw,
    unsigned short* __restrict__ wtd, unsigned short* __restrict__ wtc,
    unsigned short* __restrict__ offwtb,
    float* __restrict__ style0, float* __restrict__ style1, float* __restrict__ tproj)
{
  int blk = blockIdx.x, t = threadIdx.x;
  if (blk < 2304) {                       // dcn pack: e=((k*32+c8)*256+o)*8+j
    int e = blk*256 + t;
    int j = e & 7, o = (e >> 3) & 255, c8 = (e >> 11) & 31, k = e >> 16;
    wtd[e] = f2bf(dcn_w[((o*256 + c8*8 + j)*9) + k]);
  } else if (blk < 4608) {                // conv1 pack
    int e = (blk-2304)*256 + t;
    int j = e & 7, o = (e >> 3) & 255, c8 = (e >> 11) & 31, k = e >> 16;
    wtc[e] = f2bf(c1w[((o*256 + c8*8 + j)*9) + k]);
  } else if (blk < 4896) {                // offw pack: [9][32 c8][32 o][8 j], oc>=27 -> 0
    int e = (blk-4608)*256 + t;           // 73728 elems
    int j = e & 7, o = (e >> 3) & 31, c8 = (e >> 8) & 31, k = e >> 13;
    int c = c8*8 + j;
    offwtb[e] = (o < 27) ? f2bf(offw[((o*256 + c)*9) + k]) : (unsigned short)0;
  } else if (blk < 4912) {                // style0 = zemb @ g0w.T + g0b (8x512)
    int e = (blk-4896)*256 + t; int b = e >> 9, j = e & 511;
    float s = g0b[j];
    const float* z = zemb + b*256; const float* w = g0w + j*256;
    for (int i = 0; i < 256; ++i) s += z[i]*w[i];
    style0[e] = s;
  } else if (blk < 4928) {                // style1
    int e = (blk-4912)*256 + t; int b = e >> 9, j = e & 511;
    float s = g1b[j];
    const float* z = zemb + b*256; const float* w = g1w + j*256;
    for (int i = 0; i < 256; ++i) s += z[i]*w[i];
    style1[e] = s;
  } else {                                // tproj = silu(temb) @ d0w.T + d0b (8x256)
    int e = (blk-4928)*256 + t; int b = e >> 8, o = e & 255;
    float s = d0b[o];
    const float* tb = temb + b*512; const float* w = d0w + o*512;
    for (int i = 0; i < 512; ++i) s += silu_f(tb[i])*w[i];
    tproj[e] = s;
  }
}

// ---------- reductions ----------
__device__ __forceinline__ void block_reduce2(float& s, float& q){
  for (int off = 32; off > 0; off >>= 1) {
    s += __shfl_down(s, off, 64);
    q += __shfl_down(q, off, 64);
  }
  __shared__ float ss[4], qs[4];
  int wid = threadIdx.x >> 6, lane = threadIdx.x & 63;
  if (lane == 0) { ss[wid] = s; qs[wid] = q; }
  __syncthreads();
  if (threadIdx.x == 0) { s = ss[0]+ss[1]+ss[2]+ss[3]; q = qs[0]+qs[1]+qs[2]+qs[3]; }
}

__global__ __launch_bounds__(256) void gn0_stats_kernel(
    const float* __restrict__ x, float* __restrict__ mu, float* __restrict__ rs)
{
  int blk = blockIdx.x;  // b*32+g ; NCHW group = 32768 contiguous
  const float4* p4 = (const float4*)(x + (size_t)blk*32768);
  float s = 0.f, q = 0.f;
  for (int i = threadIdx.x; i < 8192; i += 256) {
    float4 v = p4[i];
    s += v.x+v.y+v.z+v.w;
    q += v.x*v.x + v.y*v.y + v.z*v.z + v.w*v.w;
  }
  block_reduce2(s, q);
  if (threadIdx.x == 0) {
    float m = s * (1.f/32768.f);
    float var = q * (1.f/32768.f) - m*m;
    mu[blk] = m; rs[blk] = rsqrtf(var + EPSV);
  }
}

// GN stats over h1b (bf16 NHWC)
__global__ __launch_bounds__(256) void gn1_stats_kernel(
    const unsigned short* __restrict__ h1b, float* __restrict__ mu, float* __restrict__ rs)
{
  int blk = blockIdx.x;  // b*32+g
  int b = blk >> 5, g = blk & 31;
  const unsigned short* base = h1b + (size_t)b*1048576 + g*8;
  float s = 0.f, q = 0.f;
  for (int px = threadIdx.x; px < 4096; px += 256) {
    bf16x8 v = *(const bf16x8*)(base + (size_t)px*256);
    #pragma unroll
    for (int e = 0; e < 8; ++e) {
      float f = bf2f((unsigned short)v[e]);
      s += f; q += f*f;
    }
  }
  block_reduce2(s, q);
  if (threadIdx.x == 0) {
    float m = s * (1.f/32768.f);
    float var = q * (1.f/32768.f) - m*m;
    mu[blk] = m; rs[blk] = rsqrtf(var + EPSV);
  }
}

// ---------- h0 = silu(adagn(x)) NCHW -> NHWC bf16 ----------
__global__ __launch_bounds__(256) void h0_kernel(
    const float* __restrict__ x, const float* __restrict__ style0,
    const float* __restrict__ mu, const float* __restrict__ rs,
    unsigned short* __restrict__ h0b)
{
  int blk = blockIdx.x;          // b(8) x ptile(64) x ctile(8)
  int b  = blk >> 9;
  int pt = (blk >> 3) & 63;
  int ct = blk & 7;
  __shared__ float tile[32][65];
  int p0 = pt*64, c0 = ct*32;
  int t = threadIdx.x;
  for (int it = 0; it < 8; ++it) {
    int c = c0 + it*4 + (t >> 6);
    int p = p0 + (t & 63);
    float v = x[((size_t)(b*256 + c))*4096 + p];
    int g = c >> 3;
    float m  = mu[b*32+g], r = rs[b*32+g];
    float ga = style0[b*512 + c], be = style0[b*512 + 256 + c];
    float u = ga * (v - m) * r + be;
    tile[c - c0][p - p0] = silu_f(u);
  }
  __syncthreads();
  for (int it = 0; it < 8; ++it) {
    int pp = it*8 + (t >> 5);
    int cc = t & 31;
    h0b[((size_t)(b*4096 + p0 + pp))*256 + c0 + cc] = f2bf(tile[cc][pp]);
  }
}

// ---------- offset conv MFMA: 32 px x 32 oc (27 used), K=2304 ----------
__global__ __launch_bounds__(256) void offset_mfma_kernel(
    const unsigned short* __restrict__ h0b, const unsigned short* __restrict__ wt,
    const float* __restrict__ off_b, float* __restrict__ off_t)
{
  int bid = blockIdx.x;
  int b  = bid & 7;                            // XCD swizzle
  int p0 = (bid >> 3) * 32;
  int y = p0 >> 6, xb = p0 & 63;
  int t = threadIdx.x;
  int lane = t & 63, wv = t >> 6;
  int r = lane & 15, g = lane >> 4;

  __shared__ unsigned short aw[3*34*264];      // rows y-1..y+1, px xb-1..xb+32

  const unsigned short* hbase = h0b + (size_t)b*1048576;
  for (int idx = t; idx < 3264; idx += 256) {
    int row = idx / 1088, rem = idx - row*1088;
    int px = rem >> 5, c8 = rem & 31;
    int yy = y + row - 1, xx = xb - 1 + px;
    bf16x8 v = {0,0,0,0,0,0,0,0};
    if (yy >= 0 && yy < 64 && xx >= 0 && xx < 64)
      v = *(const bf16x8*)&hbase[((size_t)yy*64 + xx)*256 + c8*8];
    *(bf16x8*)&aw[(row*34 + px)*264 + c8*8] = v;
  }
  __syncthreads();

  int m = wv & 1, n = wv >> 1;                 // wave -> (px half, oc half)
  f32x4 acc = {0.f,0.f,0.f,0.f};
  for (int k = 0; k < 9; ++k) {
    int ky = k/3, kxo = k%3;
    const unsigned short* abase = &aw[(ky*34)*264];
    const unsigned short* wk = wt + (size_t)k*8192;   // [32 c8][32 o][8]
    #pragma unroll
    for (int kc = 0; kc < 8; ++kc) {
      bf16x8 a = *(const bf16x8*)&abase[(kxo + m*16 + r)*264 + kc*32 + g*8];
      bf16x8 bf = *(const bf16x8*)&wk[(size_t)((kc*4 + g)*32 + n*16 + r)*8];
      acc = __builtin_amdgcn_mfma_f32_16x16x32_bf16(a, bf, acc, 0, 0, 0);
    }
  }

  int oc = n*16 + r;
  if (oc < 27) {
    float bs = off_b[oc];
    #pragma unroll
    for (int j = 0; j < 4; ++j) {
      int px = m*16 + g*4 + j;
      off_t[((size_t)(b*4096) + p0 + px)*27 + oc] = acc[j] + bs;
    }
  }
}

// ---------- deformable conv, MFMA, double-buffered LDS ----------
__global__ __launch_bounds__(256) void deform_mfma_kernel(
    const unsigned short* __restrict__ h0b, const float* __restrict__ off_t,
    const unsigned short* __restrict__ wt, const float* __restrict__ dcn_b,
    const float* __restrict__ tproj, unsigned short* __restrict__ h1b)
{
  int bid = blockIdx.x;
  int b  = bid & 7;                            // XCD swizzle
  int p0 = (bid >> 3) * 32;                    // 32 px, same row
  int t = threadIdx.x;
  int lane = t & 63, wv = t >> 6;
  int r = lane & 15, g = lane >> 4;

  __shared__ unsigned short samp[2][32*264];   // double-buffered [px][264] bf16
  __shared__ int   iy0s[288], ix0s[288], iy1s[288], ix1s[288];
  __shared__ float w00s[288], w01s[288], w10s[288], w11s[288];

  for (int tp = t; tp < 288; tp += 256) {      // 32 px x 9 taps
    int i = tp / 9, k = tp - i*9;
    int p = p0 + i; int y = p >> 6, xq = p & 63;
    const float* ob = off_t + ((size_t)(b*4096) + p)*27;
    float dy = ob[2*k], dx = ob[2*k+1];
    float mask = 1.f / (1.f + __expf(-ob[18+k]));
    float py = dy + (float)(k/3 + y - 1);
    float px = dx + (float)(k%3 + xq - 1);
    float fy0 = floorf(py), fx0 = floorf(px);
    float wy1 = py - fy0, wx1 = px - fx0;
    int y0 = (int)fy0, x0 = (int)fx0, y1 = y0+1, x1 = x0+1;
    float vy0 = (y0 >= 0 && y0 < 64) ? 1.f : 0.f;
    float vy1 = (y1 >= 0 && y1 < 64) ? 1.f : 0.f;
    float vx0 = (x0 >= 0 && x0 < 64) ? 1.f : 0.f;
    float vx1 = (x1 >= 0 && x1 < 64) ? 1.f : 0.f;
    iy0s[tp] = min(max(y0,0),63); ix0s[tp] = min(max(x0,0),63);
    iy1s[tp] = min(max(y1,0),63); ix1s[tp] = min(max(x1,0),63);
    w00s[tp] = (1.f-wy1)*(1.f-wx1)*vy0*vx0*mask;
    w01s[tp] = (1.f-wy1)*wx1      *vy0*vx1*mask;
    w10s[tp] = wy1      *(1.f-wx1)*vy1*vx0*mask;
    w11s[tp] = wy1      *wx1      *vy1*vx1*mask;
  }
  __syncthreads();

  f32x4 zero4 = {0.f,0.f,0.f,0.f};
  f32x4 acc[2][4];
  #pragma unroll
  for (int m = 0; m < 2; ++m)
    #pragma unroll
    for (int n = 0; n < 4; ++n) acc[m][n] = zero4;

  const unsigned short* hb = h0b + (size_t)b*1048576;
  int px = t >> 3;                             // 8 threads per pixel
  int ci = (t & 7) * 32;                       // 32 contiguous channels each
  int o_lane = wv*64 + r;

  bf16x8 pre[16];                              // 4 corners x 32ch prefetch
  auto loadk = [&](int kk) {
    int tp = px*9 + kk;
    const bf16x8* q00 = (const bf16x8*)(hb + ((size_t)iy0s[tp]*64 + ix0s[tp])*256 + ci);
    const bf16x8* q01 = (const bf16x8*)(hb + ((size_t)iy0s[tp]*64 + ix1s[tp])*256 + ci);
    const bf16x8* q10 = (const bf16x8*)(hb + ((size_t)iy1s[tp]*64 + ix0s[tp])*256 + ci);
    const bf16x8* q11 = (const bf16x8*)(hb + ((size_t)iy1s[tp]*64 + ix1s[tp])*256 + ci);
    pre[0] = q00[0]; pre[1] = q00[1]; pre[2] = q00[2]; pre[3] = q00[3];
    pre[4] = q01[0]; pre[5] = q01[1]; pre[6] = q01[2]; pre[7] = q01[3];
    pre[8] = q10[0]; pre[9] = q10[1]; pre[10] = q10[2]; pre[11] = q10[3];
    pre[12] = q11[0]; pre[13] = q11[1]; pre[14] = q11[2]; pre[15] = q11[3];
  };

  loadk(0);
  for (int k = 0; k < 9; ++k) {
    { // cvt + weighted sum from prefetch regs -> LDS buf k&1
      int tp = px*9 + k;
      float a00 = w00s[tp], a01 = w01s[tp], a10 = w10s[tp], a11 = w11s[tp];
      unsigned short* sp = &samp[k & 1][px*264 + ci];
      #pragma unroll
      for (int ch = 0; ch < 4; ++ch) {
        bf16x8 o;
        #pragma unroll
        for (int e = 0; e < 8; ++e) {
          float v = a00*bf2f((unsigned short)pre[ch][e])
                  + a01*bf2f((unsigned short)pre[4+ch][e])
                  + a10*bf2f((unsigned short)pre[8+ch][e])
                  + a11*bf2f((unsigned short)pre[12+ch][e]);
          o[e] = (short)f2bf(v);
        }
        *(bf16x8*)(sp + ch*8) = o;
      }
    }
    if (k < 8) loadk(k+1);                     // issue next-tap loads early
    __syncthreads();                           // ONE barrier per tap (dbuf)

    const unsigned short* sb = samp[k & 1];
    const unsigned short* wk = wt + (size_t)k*65536;   // [32][256][8] this tap
    #pragma unroll
    for (int kc = 0; kc < 8; ++kc) {
      bf16x8 a0 = *(const bf16x8*)&sb[(     r)*264 + kc*32 + g*8];
      bf16x8 a1 = *(const bf16x8*)&sb[(16 + r)*264 + kc*32 + g*8];
      const unsigned short* wb = wk + (size_t)(kc*4 + g)*2048 + o_lane*8;
      bf16x8 b0 = *(const bf16x8*)&wb[  0*8];
      bf16x8 b1 = *(const bf16x8*)&wb[ 16*8];
      bf16x8 b2 = *(const bf16x8*)&wb[ 32*8];
      bf16x8 b3 = *(const bf16x8*)&wb[ 48*8];
      acc[0][0] = __builtin_amdgcn_mfma_f32_16x16x32_bf16(a0, b0, acc[0][0], 0, 0, 0);
      acc[0][1] = __builtin_amdgcn_mfma_f32_16x16x32_bf16(a0, b1, acc[0][1], 0, 0, 0);
      acc[0][2] = __builtin_amdgcn_mfma_f32_16x16x32_bf16(a0, b2, acc[0][2], 0, 0, 0);
      acc[0][3] = __builtin_amdgcn_mfma_f32_16x16x32_bf16(a0, b3, acc[0][3], 0, 0, 0);
      acc[1][0] = __builtin_amdgcn_mfma_f32_16x16x32_bf16(a1, b0, acc[1][0], 0, 0, 0);
      acc[1][1] = __builtin_amdgcn_mfma_f32_16x16x32_bf16(a1, b1, acc[1][1], 0, 0, 0);
      acc[1][2] = __builtin_amdgcn_mfma_f32_16x16x32_bf16(a1, b2, acc[1][2], 0, 0, 0);
      acc[1][3] = __builtin_amdgcn_mfma_f32_16x16x32_bf16(a1, b3, acc[1][3], 0, 0, 0);
    }
    // no second barrier: next tap writes the other buffer
  }

  #pragma unroll
  for (int n = 0; n < 4; ++n) {
    int o = o_lane + n*16;
    float bs = dcn_b[o] + tproj[b*256 + o];
    #pragma unroll
    for (int m = 0; m < 2; ++m)
      #pragma unroll
      for (int j = 0; j < 4; ++j) {
        int pxl = m*16 + g*4 + j;
        h1b[((size_t)(b*4096) + p0 + pxl)*256 + o] = f2bf(acc[m][n][j] + bs);
      }
  }
}

// ---------- h2 = silu(adagn(h1b)) -> bf16 NHWC ----------
__global__ __launch_bounds__(256) void h2_bf16_kernel(
    const unsigned short* __restrict__ h1b, const float* __restrict__ style1,
    const float* __restrict__ mu, const float* __restrict__ rs,
    unsigned short* __restrict__ h2b)
{
  size_t i = ((size_t)blockIdx.x*256 + threadIdx.x)*8;
  bf16x8 v = *(const bf16x8*)(h1b + i);
  int b = (int)(i >> 20);
  int c0 = (int)(i & 255);
  int g = c0 >> 3;
  float m  = mu[b*32+g], rr = rs[b*32+g];
  bf16x8 o;
  #pragma unroll
  for (int j = 0; j < 8; ++j) {
    int c = c0 + j;
    float ga = style1[b*512 + c], be = style1[b*512 + 256 + c];
    float u = ga * (bf2f((unsigned short)v[j]) - m) * rr + be;
    o[j] = (short)f2bf(silu_f(u));
  }
  *(bf16x8*)(h2b + i) = o;
}

// ---------- conv1 3x3 MFMA + residual -> out NCHW ----------
__global__ __launch_bounds__(256) void conv1_mfma_kernel(
    const unsigned short* __restrict__ h2b, const unsigned short* __restrict__ wt,
    const float* __restrict__ c1_b, const float* __restrict__ x,
    float* __restrict__ out)
{
  int bid = blockIdx.x;
  int b  = bid & 7;                            // XCD swizzle
  int p0 = (bid >> 3) * 32;
  int y = p0 >> 6, xb = p0 & 63;
  int t = threadIdx.x;
  int lane = t & 63, wv = t >> 6;
  int r = lane & 15, g = lane >> 4;

  __shared__ unsigned short aw[3*34*264];

  const unsigned short* h2base = h2b + (size_t)b*1048576;
  for (int idx = t; idx < 3264; idx += 256) {
    int row = idx / 1088, rem = idx - row*1088;
    int px = rem >> 5, c8 = rem & 31;
    int yy = y + row - 1, xx = xb - 1 + px;
    bf16x8 v = {0,0,0,0,0,0,0,0};
    if (yy >= 0 && yy < 64 && xx >= 0 && xx < 64)
      v = *(const bf16x8*)&h2base[((size_t)yy*64 + xx)*256 + c8*8];
    *(bf16x8*)&aw[(row*34 + px)*264 + c8*8] = v;
  }
  __syncthreads();

  f32x4 zero4 = {0.f,0.f,0.f,0.f};
  f32x4 acc[2][4];
  #pragma unroll
  for (int m = 0; m < 2; ++m)
    #pragma unroll
    for (int n = 0; n < 4; ++n) acc[m][n] = zero4;

  int o_lane = wv*64 + r;
  for (int k = 0; k < 9; ++k) {
    int ky = k/3, kxo = k%3;
    const unsigned short* abase = &aw[(ky*34)*264];
    const unsigned short* wk = wt + (size_t)k*65536;
    #pragma unroll
    for (int kc = 0; kc < 8; ++kc) {
      bf16x8 a0 = *(const bf16x8*)&abase[(kxo +      r)*264 + kc*32 + g*8];
      bf16x8 a1 = *(const bf16x8*)&abase[(kxo + 16 + r)*264 + kc*32 + g*8];
      const unsigned short* wb = wk + (size_t)(kc*4 + g)*2048 + o_lane*8;
      bf16x8 b0 = *(const bf16x8*)&wb[  0*8];
      bf16x8 b1 = *(const bf16x8*)&wb[ 16*8];
      bf16x8 b2 = *(const bf16x8*)&wb[ 32*8];
      bf16x8 b3 = *(const bf16x8*)&wb[ 48*8];
      acc[0][0] = __builtin_amdgcn_mfma_f32_16x16x32_bf16(a0, b0, acc[0][0], 0, 0, 0);
      acc[0][1] = __builtin_amdgcn_mfma_f32_16x16x32_bf16(a0, b1, acc[0][1], 0, 0, 0);
      acc[0][2] = __builtin_amdgcn_mfma_f32_16x16x32_bf16(a0, b2, acc[0][2], 0, 0, 0);
      acc[0][3] = __builtin_amdgcn_mfma_f32_16x16x32_bf16(a0, b3, acc[0][3], 0, 0, 0);
      acc[1][0] = __builtin_amdgcn_mfma_f32_16x16x32_bf16(a1, b0, acc[1][0], 0, 0, 0);
      acc[1][1] = __builtin_amdgcn_mfma_f32_16x16x32_bf16(a1, b1, acc[1][1], 0, 0, 0);
      acc[1][2] = __builtin_amdgcn_mfma_f32_16x16x32_bf16(a1, b2, acc[1][2], 0, 0, 0);
      acc[1][3] = __builtin_amdgcn_mfma_f32_16x16x32_bf16(a1, b3, acc[1][3], 0, 0, 0);
    }
  }

  #pragma unroll
  for (int n = 0; n < 4; ++n) {
    int o = o_lane + n*16;
    float cb = c1_b[o];
    #pragma unroll
    for (int m = 0; m < 2; ++m)
      #pragma unroll
      for (int j = 0; j < 4; ++j) {
        int pxl = m*16 + g*4 + j;
        size_t oi = ((size_t)(b*256 + o))*4096 + p0 + pxl;
        out[oi] = x[oi] + acc[m][n][j] + cb;
      }
  }
}

extern "C" void kernel_launch(void* const* d_in, const int* in_sizes, int n_in,
                              void* d_out, int out_size, void* d_ws, size_t ws_size,
                              hipStream_t stream) {
  const float* x    = (const float*)d_in[0];
  const float* temb = (const float*)d_in[1];
  const float* zemb = (const float*)d_in[2];
  const float* g0w  = (const float*)d_in[3];
  const float* g0b  = (const float*)d_in[4];
  const float* offw = (const float*)d_in[5];
  const float* offb = (const float*)d_in[6];
  const float* dcnw = (const float*)d_in[7];
  const float* dcnb = (const float*)d_in[8];
  const float* d0w  = (const float*)d_in[9];
  const float* d0b  = (const float*)d_in[10];
  const float* g1w  = (const float*)d_in[11];
  const float* g1b  = (const float*)d_in[12];
  const float* c1w  = (const float*)d_in[13];
  const float* c1b  = (const float*)d_in[14];
  float* out = (float*)d_out;
  float* ws  = (float*)d_ws;

  unsigned short* h0b = (unsigned short*)(ws + WS_H0B);
  unsigned short* h1b = (unsigned short*)(ws + WS_H1B);
  float* off_t   = ws + WS_OFFT;
  unsigned short* wtd  = (unsigned short*)(ws + WS_WTD);
  unsigned short* wtc  = (unsigned short*)(ws + WS_WTC);
  unsigned short* owtb = (unsigned short*)(ws + WS_OFFWTB);
  float* style0  = ws + WS_STYLE0;
  float* style1  = ws + WS_STYLE1;
  float* tproj   = ws + WS_TPROJ;
  float* mu0     = ws + WS_MU0;
  float* rs0     = ws + WS_RS0;
  float* mu1     = ws + WS_MU1;
  float* rs1     = ws + WS_RS1;
  unsigned short* h2b = (unsigned short*)(ws + WS_H0B);  // reuse (h0 dead after deform)

  prep_kernel<<<4936, 256, 0, stream>>>(zemb, temb, g0w, g0b, g1w, g1b, d0w, d0b,
                                        dcnw, c1w, offw, wtd, wtc, owtb,
                                        style0, style1, tproj);
  gn0_stats_kernel<<<256, 256, 0, stream>>>(x, mu0, rs0);
  h0_kernel<<<4096, 256, 0, stream>>>(x, style0, mu0, rs0, h0b);
  offset_mfma_kernel<<<1024, 256, 0, stream>>>(h0b, owtb, offb, off_t);
  deform_mfma_kernel<<<1024, 256, 0, stream>>>(h0b, off_t, wtd, dcnb, tproj, h1b);
  gn1_stats_kernel<<<256, 256, 0, stream>>>(h1b, mu1, rs1);
  h2_bf16_kernel<<<4096, 256, 0, stream>>>(h1b, style1, mu1, rs1, h2b);
  conv1_mfma_kernel<<<1024, 256, 0, stream>>>(h2b, wtc, c1b, x, out);
}

// Round 10
// 274.967 us; speedup vs baseline: 3.9817x; 1.0057x over previous
//
#include <hip/hip_runtime.h>
#include <hip/hip_bf16.h>

// ResnetBlockDDPMpp_Adagn: B=8, CIN=COUT=256, H=W=64, G=32, K=3
// Round 10 (on R9 pass, 276us):
//  - R9: dbuf gained only 7us; VGPR=104 proves pre[16] (64 regs) never stayed
//    resident -> compiler sank loads to use site -> latency exposed per tap.
//  - Fix: deform 512 thr / 8 waves. Gather = 16thr/px x 16ch -> pre[8]=32 regs
//    (fits). MFMA = 8 waves x (2M x 4N), acc[4]. Same verified frag layout,
//    same dbuf, same 43KB LDS (3 blocks/CU -> up to 24 waves).

#define EPSV 1e-6f

typedef short  bf16x8 __attribute__((ext_vector_type(8)));
typedef float  f32x4  __attribute__((ext_vector_type(4)));

__device__ __forceinline__ float silu_f(float v){ return v / (1.f + __expf(-v)); }
__device__ __forceinline__ unsigned short f2bf(float f){
  unsigned int u = __float_as_uint(f);
  u = (u + 0x7FFFu + ((u >> 16) & 1u)) >> 16;
  return (unsigned short)u;
}
__device__ __forceinline__ float bf2f(unsigned short u){
  return __uint_as_float(((unsigned int)u) << 16);
}

// ---------------- ws layout (float units) ----------------
// sizes (floats): h0b 4194304 | h1b 4194304 | offt 884736 | wtd 294912
//                 wtc 294912 | owtb 36864 | st0 4096 | st1 4096 | tproj 2048
#define WS_H0B     0            // 8*4096*256 bf16 (reused as h2 bf16)
#define WS_H1B     4194304      // 8*4096*256 bf16
#define WS_OFFT    8388608      // 8*4096*27 fp32
#define WS_WTD     9273344      // dcn bf16 [9][32][256][8]
#define WS_WTC     9568256      // conv1 bf16 same
#define WS_OFFWTB  9863168      // offw bf16 [9][32][32][8]
#define WS_STYLE0  9900032
#define WS_STYLE1  9904128
#define WS_TPROJ   9908224
#define WS_MU0     9910272
#define WS_RS0     9910528
#define WS_MU1     9910784
#define WS_RS1     9911040
// end 9,911,296 floats = 39.6 MB

// ---------- prep: weight packs + tiny GEMMs ----------
__global__ __launch_bounds__(256) void prep_kernel(
    const float* __restrict__ zemb, const float* __restrict__ temb,
    const float* __restrict__ g0w, const float* __restrict__ g0b,
    const float* __restrict__ g1w, const float* __restrict__ g1b,
    const float* __restrict__ d0w, const float* __restrict__ d0b,
    const float* __restrict__ dcn_w, const float* __restrict__ c1w,
    const float* __restrict__ offw,
    unsigned short* __restrict__ wtd, unsigned short* __restrict__ wtc,
    unsigned short* __restrict__ offwtb,
    float* __restrict__ style0, float* __restrict__ style1, float* __restrict__ tproj)
{
  int blk = blockIdx.x, t = threadIdx.x;
  if (blk < 2304) {                       // dcn pack: e=((k*32+c8)*256+o)*8+j
    int e = blk*256 + t;
    int j = e & 7, o = (e >> 3) & 255, c8 = (e >> 11) & 31, k = e >> 16;
    wtd[e] = f2bf(dcn_w[((o*256 + c8*8 + j)*9) + k]);
  } else if (blk < 4608) {                // conv1 pack
    int e = (blk-2304)*256 + t;
    int j = e & 7, o = (e >> 3) & 255, c8 = (e >> 11) & 31, k = e >> 16;
    wtc[e] = f2bf(c1w[((o*256 + c8*8 + j)*9) + k]);
  } else if (blk < 4896) {                // offw pack: [9][32 c8][32 o][8 j], oc>=27 -> 0
    int e = (blk-4608)*256 + t;           // 73728 elems
    int j = e & 7, o = (e >> 3) & 31, c8 = (e >> 8) & 31, k = e >> 13;
    int c = c8*8 + j;
    offwtb[e] = (o < 27) ? f2bf(offw[((o*256 + c)*9) + k]) : (unsigned short)0;
  } else if (blk < 4912) {                // style0 = zemb @ g0w.T + g0b (8x512)
    int e = (blk-4896)*256 + t; int b = e >> 9, j = e & 511;
    float s = g0b[j];
    const float* z = zemb + b*256; const float* w = g0w + j*256;
    for (int i = 0; i < 256; ++i) s += z[i]*w[i];
    style0[e] = s;
  } else if (blk < 4928) {                // style1
    int e = (blk-4912)*256 + t; int b = e >> 9, j = e & 511;
    float s = g1b[j];
    const float* z = zemb + b*256; const float* w = g1w + j*256;
    for (int i = 0; i < 256; ++i) s += z[i]*w[i];
    style1[e] = s;
  } else {                                // tproj = silu(temb) @ d0w.T + d0b (8x256)
    int e = (blk-4928)*256 + t; int b = e >> 8, o = e & 255;
    float s = d0b[o];
    const float* tb = temb + b*512; const float* w = d0w + o*512;
    for (int i = 0; i < 512; ++i) s += silu_f(tb[i])*w[i];
    tproj[e] = s;
  }
}

// ---------- reductions ----------
__device__ __forceinline__ void block_reduce2(float& s, float& q){
  for (int off = 32; off > 0; off >>= 1) {
    s += __shfl_down(s, off, 64);
    q += __shfl_down(q, off, 64);
  }
  __shared__ float ss[4], qs[4];
  int wid = threadIdx.x >> 6, lane = threadIdx.x & 63;
  if (lane == 0) { ss[wid] = s; qs[wid] = q; }
  __syncthreads();
  if (threadIdx.x == 0) { s = ss[0]+ss[1]+ss[2]+ss[3]; q = qs[0]+qs[1]+qs[2]+qs[3]; }
}

__global__ __launch_bounds__(256) void gn0_stats_kernel(
    const float* __restrict__ x, float* __restrict__ mu, float* __restrict__ rs)
{
  int blk = blockIdx.x;  // b*32+g ; NCHW group = 32768 contiguous
  const float4* p4 = (const float4*)(x + (size_t)blk*32768);
  float s = 0.f, q = 0.f;
  for (int i = threadIdx.x; i < 8192; i += 256) {
    float4 v = p4[i];
    s += v.x+v.y+v.z+v.w;
    q += v.x*v.x + v.y*v.y + v.z*v.z + v.w*v.w;
  }
  block_reduce2(s, q);
  if (threadIdx.x == 0) {
    float m = s * (1.f/32768.f);
    float var = q * (1.f/32768.f) - m*m;
    mu[blk] = m; rs[blk] = rsqrtf(var + EPSV);
  }
}

// GN stats over h1b (bf16 NHWC)
__global__ __launch_bounds__(256) void gn1_stats_kernel(
    const unsigned short* __restrict__ h1b, float* __restrict__ mu, float* __restrict__ rs)
{
  int blk = blockIdx.x;  // b*32+g
  int b = blk >> 5, g = blk & 31;
  const unsigned short* base = h1b + (size_t)b*1048576 + g*8;
  float s = 0.f, q = 0.f;
  for (int px = threadIdx.x; px < 4096; px += 256) {
    bf16x8 v = *(const bf16x8*)(base + (size_t)px*256);
    #pragma unroll
    for (int e = 0; e < 8; ++e) {
      float f = bf2f((unsigned short)v[e]);
      s += f; q += f*f;
    }
  }
  block_reduce2(s, q);
  if (threadIdx.x == 0) {
    float m = s * (1.f/32768.f);
    float var = q * (1.f/32768.f) - m*m;
    mu[blk] = m; rs[blk] = rsqrtf(var + EPSV);
  }
}

// ---------- h0 = silu(adagn(x)) NCHW -> NHWC bf16 ----------
__global__ __launch_bounds__(256) void h0_kernel(
    const float* __restrict__ x, const float* __restrict__ style0,
    const float* __restrict__ mu, const float* __restrict__ rs,
    unsigned short* __restrict__ h0b)
{
  int blk = blockIdx.x;          // b(8) x ptile(64) x ctile(8)
  int b  = blk >> 9;
  int pt = (blk >> 3) & 63;
  int ct = blk & 7;
  __shared__ float tile[32][65];
  int p0 = pt*64, c0 = ct*32;
  int t = threadIdx.x;
  for (int it = 0; it < 8; ++it) {
    int c = c0 + it*4 + (t >> 6);
    int p = p0 + (t & 63);
    float v = x[((size_t)(b*256 + c))*4096 + p];
    int g = c >> 3;
    float m  = mu[b*32+g], r = rs[b*32+g];
    float ga = style0[b*512 + c], be = style0[b*512 + 256 + c];
    float u = ga * (v - m) * r + be;
    tile[c - c0][p - p0] = silu_f(u);
  }
  __syncthreads();
  for (int it = 0; it < 8; ++it) {
    int pp = it*8 + (t >> 5);
    int cc = t & 31;
    h0b[((size_t)(b*4096 + p0 + pp))*256 + c0 + cc] = f2bf(tile[cc][pp]);
  }
}

// ---------- offset conv MFMA: 32 px x 32 oc (27 used), K=2304 ----------
__global__ __launch_bounds__(256) void offset_mfma_kernel(
    const unsigned short* __restrict__ h0b, const unsigned short* __restrict__ wt,
    const float* __restrict__ off_b, float* __restrict__ off_t)
{
  int bid = blockIdx.x;
  int b  = bid & 7;                            // XCD swizzle
  int p0 = (bid >> 3) * 32;
  int y = p0 >> 6, xb = p0 & 63;
  int t = threadIdx.x;
  int lane = t & 63, wv = t >> 6;
  int r = lane & 15, g = lane >> 4;

  __shared__ unsigned short aw[3*34*264];      // rows y-1..y+1, px xb-1..xb+32

  const unsigned short* hbase = h0b + (size_t)b*1048576;
  for (int idx = t; idx < 3264; idx += 256) {
    int row = idx / 1088, rem = idx - row*1088;
    int px = rem >> 5, c8 = rem & 31;
    int yy = y + row - 1, xx = xb - 1 + px;
    bf16x8 v = {0,0,0,0,0,0,0,0};
    if (yy >= 0 && yy < 64 && xx >= 0 && xx < 64)
      v = *(const bf16x8*)&hbase[((size_t)yy*64 + xx)*256 + c8*8];
    *(bf16x8*)&aw[(row*34 + px)*264 + c8*8] = v;
  }
  __syncthreads();

  int m = wv & 1, n = wv >> 1;                 // wave -> (px half, oc half)
  f32x4 acc = {0.f,0.f,0.f,0.f};
  for (int k = 0; k < 9; ++k) {
    int ky = k/3, kxo = k%3;
    const unsigned short* abase = &aw[(ky*34)*264];
    const unsigned short* wk = wt + (size_t)k*8192;   // [32 c8][32 o][8]
    #pragma unroll
    for (int kc = 0; kc < 8; ++kc) {
      bf16x8 a = *(const bf16x8*)&abase[(kxo + m*16 + r)*264 + kc*32 + g*8];
      bf16x8 bf = *(const bf16x8*)&wk[(size_t)((kc*4 + g)*32 + n*16 + r)*8];
      acc = __builtin_amdgcn_mfma_f32_16x16x32_bf16(a, bf, acc, 0, 0, 0);
    }
  }

  int oc = n*16 + r;
  if (oc < 27) {
    float bs = off_b[oc];
    #pragma unroll
    for (int j = 0; j < 4; ++j) {
      int px = m*16 + g*4 + j;
      off_t[((size_t)(b*4096) + p0 + px)*27 + oc] = acc[j] + bs;
    }
  }
}

// ---------- deformable conv, MFMA, 512 thr / 8 waves, dbuf LDS ----------
__global__ __launch_bounds__(512) void deform_mfma_kernel(
    const unsigned short* __restrict__ h0b, const float* __restrict__ off_t,
    const unsigned short* __restrict__ wt, const float* __restrict__ dcn_b,
    const float* __restrict__ tproj, unsigned short* __restrict__ h1b)
{
  int bid = blockIdx.x;
  int b  = bid & 7;                            // XCD swizzle
  int p0 = (bid >> 3) * 32;                    // 32 px, same row
  int t = threadIdx.x;                         // 0..511
  int lane = t & 63, wv = t >> 6;              // 8 waves
  int r = lane & 15, g = lane >> 4;

  __shared__ unsigned short samp[2][32*264];   // double-buffered [px][264] bf16
  __shared__ int   iy0s[288], ix0s[288], iy1s[288], ix1s[288];
  __shared__ float w00s[288], w01s[288], w10s[288], w11s[288];

  for (int tp = t; tp < 288; tp += 512) {      // 32 px x 9 taps
    int i = tp / 9, k = tp - i*9;
    int p = p0 + i; int y = p >> 6, xq = p & 63;
    const float* ob = off_t + ((size_t)(b*4096) + p)*27;
    float dy = ob[2*k], dx = ob[2*k+1];
    float mask = 1.f / (1.f + __expf(-ob[18+k]));
    float py = dy + (float)(k/3 + y - 1);
    float px = dx + (float)(k%3 + xq - 1);
    float fy0 = floorf(py), fx0 = floorf(px);
    float wy1 = py - fy0, wx1 = px - fx0;
    int y0 = (int)fy0, x0 = (int)fx0, y1 = y0+1, x1 = x0+1;
    float vy0 = (y0 >= 0 && y0 < 64) ? 1.f : 0.f;
    float vy1 = (y1 >= 0 && y1 < 64) ? 1.f : 0.f;
    float vx0 = (x0 >= 0 && x0 < 64) ? 1.f : 0.f;
    float vx1 = (x1 >= 0 && x1 < 64) ? 1.f : 0.f;
    iy0s[tp] = min(max(y0,0),63); ix0s[tp] = min(max(x0,0),63);
    iy1s[tp] = min(max(y1,0),63); ix1s[tp] = min(max(x1,0),63);
    w00s[tp] = (1.f-wy1)*(1.f-wx1)*vy0*vx0*mask;
    w01s[tp] = (1.f-wy1)*wx1      *vy0*vx1*mask;
    w10s[tp] = wy1      *(1.f-wx1)*vy1*vx0*mask;
    w11s[tp] = wy1      *wx1      *vy1*vx1*mask;
  }
  __syncthreads();

  f32x4 zero4 = {0.f,0.f,0.f,0.f};
  f32x4 acc[4] = {zero4, zero4, zero4, zero4};

  const unsigned short* hb = h0b + (size_t)b*1048576;
  int px = t >> 4;                             // 16 threads per pixel
  int ci = (t & 15) * 16;                      // 16 contiguous channels each
  int m = wv & 1, n = wv >> 1;                 // (px half, oc quarter)
  int o_base = n*64 + r;

  bf16x8 pre[8];                               // 4 corners x 16ch = 32 VGPRs
  auto loadk = [&](int kk) {
    int tp = px*9 + kk;
    const bf16x8* q00 = (const bf16x8*)(hb + ((size_t)iy0s[tp]*64 + ix0s[tp])*256 + ci);
    const bf16x8* q01 = (const bf16x8*)(hb + ((size_t)iy0s[tp]*64 + ix1s[tp])*256 + ci);
    const bf16x8* q10 = (const bf16x8*)(hb + ((size_t)iy1s[tp]*64 + ix0s[tp])*256 + ci);
    const bf16x8* q11 = (const bf16x8*)(hb + ((size_t)iy1s[tp]*64 + ix1s[tp])*256 + ci);
    pre[0] = q00[0]; pre[1] = q00[1];
    pre[2] = q01[0]; pre[3] = q01[1];
    pre[4] = q10[0]; pre[5] = q10[1];
    pre[6] = q11[0]; pre[7] = q11[1];
  };

  loadk(0);
  for (int k = 0; k < 9; ++k) {
    { // cvt + weighted sum from prefetch regs -> LDS buf k&1
      int tp = px*9 + k;
      float a00 = w00s[tp], a01 = w01s[tp], a10 = w10s[tp], a11 = w11s[tp];
      unsigned short* sp = &samp[k & 1][px*264 + ci];
      #pragma unroll
      for (int ch = 0; ch < 2; ++ch) {
        bf16x8 o;
        #pragma unroll
        for (int e = 0; e < 8; ++e) {
          float v = a00*bf2f((unsigned short)pre[ch][e])
                  + a01*bf2f((unsigned short)pre[2+ch][e])
                  + a10*bf2f((unsigned short)pre[4+ch][e])
                  + a11*bf2f((unsigned short)pre[6+ch][e]);
          o[e] = (short)f2bf(v);
        }
        *(bf16x8*)(sp + ch*8) = o;
      }
    }
    if (k < 8) loadk(k+1);                     // next-tap loads: pre[8] fits in regs
    __syncthreads();                           // ONE barrier per tap (dbuf)

    const unsigned short* sb = samp[k & 1];
    const unsigned short* wk = wt + (size_t)k*65536;   // [32][256][8] this tap
    #pragma unroll
    for (int kc = 0; kc < 8; ++kc) {
      bf16x8 a = *(const bf16x8*)&sb[(m*16 + r)*264 + kc*32 + g*8];
      const unsigned short* wb = wk + (size_t)(kc*4 + g)*2048 + o_base*8;
      bf16x8 b0 = *(const bf16x8*)&wb[  0*8];
      bf16x8 b1 = *(const bf16x8*)&wb[ 16*8];
      bf16x8 b2 = *(const bf16x8*)&wb[ 32*8];
      bf16x8 b3 = *(const bf16x8*)&wb[ 48*8];
      acc[0] = __builtin_amdgcn_mfma_f32_16x16x32_bf16(a, b0, acc[0], 0, 0, 0);
      acc[1] = __builtin_amdgcn_mfma_f32_16x16x32_bf16(a, b1, acc[1], 0, 0, 0);
      acc[2] = __builtin_amdgcn_mfma_f32_16x16x32_bf16(a, b2, acc[2], 0, 0, 0);
      acc[3] = __builtin_amdgcn_mfma_f32_16x16x32_bf16(a, b3, acc[3], 0, 0, 0);
    }
    // no second barrier: next tap writes the other buffer
  }

  #pragma unroll
  for (int nn = 0; nn < 4; ++nn) {
    int o = o_base + nn*16;
    float bs = dcn_b[o] + tproj[b*256 + o];
    #pragma unroll
    for (int j = 0; j < 4; ++j) {
      int pxl = m*16 + g*4 + j;
      h1b[((size_t)(b*4096) + p0 + pxl)*256 + o] = f2bf(acc[nn][j] + bs);
    }
  }
}

// ---------- h2 = silu(adagn(h1b)) -> bf16 NHWC ----------
__global__ __launch_bounds__(256) void h2_bf16_kernel(
    const unsigned short* __restrict__ h1b, const float* __restrict__ style1,
    const float* __restrict__ mu, const float* __restrict__ rs,
    unsigned short* __restrict__ h2b)
{
  size_t i = ((size_t)blockIdx.x*256 + threadIdx.x)*8;
  bf16x8 v = *(const bf16x8*)(h1b + i);
  int b = (int)(i >> 20);
  int c0 = (int)(i & 255);
  int g = c0 >> 3;
  float m  = mu[b*32+g], rr = rs[b*32+g];
  bf16x8 o;
  #pragma unroll
  for (int j = 0; j < 8; ++j) {
    int c = c0 + j;
    float ga = style1[b*512 + c], be = style1[b*512 + 256 + c];
    float u = ga * (bf2f((unsigned short)v[j]) - m) * rr + be;
    o[j] = (short)f2bf(silu_f(u));
  }
  *(bf16x8*)(h2b + i) = o;
}

// ---------- conv1 3x3 MFMA + residual -> out NCHW ----------
__global__ __launch_bounds__(256) void conv1_mfma_kernel(
    const unsigned short* __restrict__ h2b, const unsigned short* __restrict__ wt,
    const float* __restrict__ c1_b, const float* __restrict__ x,
    float* __restrict__ out)
{
  int bid = blockIdx.x;
  int b  = bid & 7;                            // XCD swizzle
  int p0 = (bid >> 3) * 32;
  int y = p0 >> 6, xb = p0 & 63;
  int t = threadIdx.x;
  int lane = t & 63, wv = t >> 6;
  int r = lane & 15, g = lane >> 4;

  __shared__ unsigned short aw[3*34*264];

  const unsigned short* h2base = h2b + (size_t)b*1048576;
  for (int idx = t; idx < 3264; idx += 256) {
    int row = idx / 1088, rem = idx - row*1088;
    int px = rem >> 5, c8 = rem & 31;
    int yy = y + row - 1, xx = xb - 1 + px;
    bf16x8 v = {0,0,0,0,0,0,0,0};
    if (yy >= 0 && yy < 64 && xx >= 0 && xx < 64)
      v = *(const bf16x8*)&h2base[((size_t)yy*64 + xx)*256 + c8*8];
    *(bf16x8*)&aw[(row*34 + px)*264 + c8*8] = v;
  }
  __syncthreads();

  f32x4 zero4 = {0.f,0.f,0.f,0.f};
  f32x4 acc[2][4];
  #pragma unroll
  for (int m = 0; m < 2; ++m)
    #pragma unroll
    for (int n = 0; n < 4; ++n) acc[m][n] = zero4;

  int o_lane = wv*64 + r;
  for (int k = 0; k < 9; ++k) {
    int ky = k/3, kxo = k%3;
    const unsigned short* abase = &aw[(ky*34)*264];
    const unsigned short* wk = wt + (size_t)k*65536;
    #pragma unroll
    for (int kc = 0; kc < 8; ++kc) {
      bf16x8 a0 = *(const bf16x8*)&abase[(kxo +      r)*264 + kc*32 + g*8];
      bf16x8 a1 = *(const bf16x8*)&abase[(kxo + 16 + r)*264 + kc*32 + g*8];
      const unsigned short* wb = wk + (size_t)(kc*4 + g)*2048 + o_lane*8;
      bf16x8 b0 = *(const bf16x8*)&wb[  0*8];
      bf16x8 b1 = *(const bf16x8*)&wb[ 16*8];
      bf16x8 b2 = *(const bf16x8*)&wb[ 32*8];
      bf16x8 b3 = *(const bf16x8*)&wb[ 48*8];
      acc[0][0] = __builtin_amdgcn_mfma_f32_16x16x32_bf16(a0, b0, acc[0][0], 0, 0, 0);
      acc[0][1] = __builtin_amdgcn_mfma_f32_16x16x32_bf16(a0, b1, acc[0][1], 0, 0, 0);
      acc[0][2] = __builtin_amdgcn_mfma_f32_16x16x32_bf16(a0, b2, acc[0][2], 0, 0, 0);
      acc[0][3] = __builtin_amdgcn_mfma_f32_16x16x32_bf16(a0, b3, acc[0][3], 0, 0, 0);
      acc[1][0] = __builtin_amdgcn_mfma_f32_16x16x32_bf16(a1, b0, acc[1][0], 0, 0, 0);
      acc[1][1] = __builtin_amdgcn_mfma_f32_16x16x32_bf16(a1, b1, acc[1][1], 0, 0, 0);
      acc[1][2] = __builtin_amdgcn_mfma_f32_16x16x32_bf16(a1, b2, acc[1][2], 0, 0, 0);
      acc[1][3] = __builtin_amdgcn_mfma_f32_16x16x32_bf16(a1, b3, acc[1][3], 0, 0, 0);
    }
  }

  #pragma unroll
  for (int n = 0; n < 4; ++n) {
    int o = o_lane + n*16;
    float cb = c1_b[o];
    #pragma unroll
    for (int m = 0; m < 2; ++m)
      #pragma unroll
      for (int j = 0; j < 4; ++j) {
        int pxl = m*16 + g*4 + j;
        size_t oi = ((size_t)(b*256 + o))*4096 + p0 + pxl;
        out[oi] = x[oi] + acc[m][n][j] + cb;
      }
  }
}

extern "C" void kernel_launch(void* const* d_in, const int* in_sizes, int n_in,
                              void* d_out, int out_size, void* d_ws, size_t ws_size,
                              hipStream_t stream) {
  const float* x    = (const float*)d_in[0];
  const float* temb = (const float*)d_in[1];
  const float* zemb = (const float*)d_in[2];
  const float* g0w  = (const float*)d_in[3];
  const float* g0b  = (const float*)d_in[4];
  const float* offw = (const float*)d_in[5];
  const float* offb = (const float*)d_in[6];
  const float* dcnw = (const float*)d_in[7];
  const float* dcnb = (const float*)d_in[8];
  const float* d0w  = (const float*)d_in[9];
  const float* d0b  = (const float*)d_in[10];
  const float* g1w  = (const float*)d_in[11];
  const float* g1b  = (const float*)d_in[12];
  const float* c1w  = (const float*)d_in[13];
  const float* c1b  = (const float*)d_in[14];
  float* out = (float*)d_out;
  float* ws  = (float*)d_ws;

  unsigned short* h0b = (unsigned short*)(ws + WS_H0B);
  unsigned short* h1b = (unsigned short*)(ws + WS_H1B);
  float* off_t   = ws + WS_OFFT;
  unsigned short* wtd  = (unsigned short*)(ws + WS_WTD);
  unsigned short* wtc  = (unsigned short*)(ws + WS_WTC);
  unsigned short* owtb = (unsigned short*)(ws + WS_OFFWTB);
  float* style0  = ws + WS_STYLE0;
  float* style1  = ws + WS_STYLE1;
  float* tproj   = ws + WS_TPROJ;
  float* mu0     = ws + WS_MU0;
  float* rs0     = ws + WS_RS0;
  float* mu1     = ws + WS_MU1;
  float* rs1     = ws + WS_RS1;
  unsigned short* h2b = (unsigned short*)(ws + WS_H0B);  // reuse (h0 dead after deform)

  prep_kernel<<<4936, 256, 0, stream>>>(zemb, temb, g0w, g0b, g1w, g1b, d0w, d0b,
                                        dcnw, c1w, offw, wtd, wtc, owtb,
                                        style0, style1, tproj);
  gn0_stats_kernel<<<256, 256, 0, stream>>>(x, mu0, rs0);
  h0_kernel<<<4096, 256, 0, stream>>>(x, style0, mu0, rs0, h0b);
  offset_mfma_kernel<<<1024, 256, 0, stream>>>(h0b, owtb, offb, off_t);
  deform_mfma_kernel<<<1024, 512, 0, stream>>>(h0b, off_t, wtd, dcnb, tproj, h1b);
  gn1_stats_kernel<<<256, 256, 0, stream>>>(h1b, mu1, rs1);
  h2_bf16_kernel<<<4096, 256, 0, stream>>>(h1b, style1, mu1, rs1, h2b);
  conv1_mfma_kernel<<<1024, 256, 0, stream>>>(h2b, wtc, c1b, x, out);
}

// Round 12
// 267.452 us; speedup vs baseline: 4.0936x; 1.0281x over previous
//
#include <hip/hip_runtime.h>
#include <hip/hip_bf16.h>

// ResnetBlockDDPMpp_Adagn: B=8, CIN=COUT=256, H=W=64, G=32, K=3
// Round 12: identical to R11 (broker container died before any measurement).
//  - R10 lesson: occupancy 2x'd, VGPR fixed -> dur FLAT. Real limiter: L2
//    weight stream. Per block per tap 128KB of dcn weights, and R10's wave
//    map (n=wv>>1) made wave PAIRS load the same slice (x2). Per CU 9.2MB
//    @135GB/s = 68us ~= the whole kernel.
//  - Fix: (a) 8 waves x UNIQUE 32-out slice (no redundancy); (b) M-tile 64px
//    (full row, 512 blocks) -> per-CU weight stream 9.2 -> 2.3MB. Same for
//    conv1. LDS 86KB/102KB -> 1 block/CU (occupancy proven not the limiter).

#define EPSV 1e-6f

typedef short  bf16x8 __attribute__((ext_vector_type(8)));
typedef float  f32x4  __attribute__((ext_vector_type(4)));

__device__ __forceinline__ float silu_f(float v){ return v / (1.f + __expf(-v)); }
__device__ __forceinline__ unsigned short f2bf(float f){
  unsigned int u = __float_as_uint(f);
  u = (u + 0x7FFFu + ((u >> 16) & 1u)) >> 16;
  return (unsigned short)u;
}
__device__ __forceinline__ float bf2f(unsigned short u){
  return __uint_as_float(((unsigned int)u) << 16);
}

// ---------------- ws layout (float units) ----------------
// sizes (floats): h0b 4194304 | h1b 4194304 | offt 884736 | wtd 294912
//                 wtc 294912 | owtb 36864 | st0 4096 | st1 4096 | tproj 2048
#define WS_H0B     0            // 8*4096*256 bf16 (reused as h2 bf16)
#define WS_H1B     4194304      // 8*4096*256 bf16
#define WS_OFFT    8388608      // 8*4096*27 fp32
#define WS_WTD     9273344      // dcn bf16 [9][32][256][8]
#define WS_WTC     9568256      // conv1 bf16 same
#define WS_OFFWTB  9863168      // offw bf16 [9][32][32][8]
#define WS_STYLE0  9900032
#define WS_STYLE1  9904128
#define WS_TPROJ   9908224
#define WS_MU0     9910272
#define WS_RS0     9910528
#define WS_MU1     9910784
#define WS_RS1     9911040
// end 9,911,296 floats = 39.6 MB

// ---------- prep: weight packs + tiny GEMMs ----------
__global__ __launch_bounds__(256) void prep_kernel(
    const float* __restrict__ zemb, const float* __restrict__ temb,
    const float* __restrict__ g0w, const float* __restrict__ g0b,
    const float* __restrict__ g1w, const float* __restrict__ g1b,
    const float* __restrict__ d0w, const float* __restrict__ d0b,
    const float* __restrict__ dcn_w, const float* __restrict__ c1w,
    const float* __restrict__ offw,
    unsigned short* __restrict__ wtd, unsigned short* __restrict__ wtc,
    unsigned short* __restrict__ offwtb,
    float* __restrict__ style0, float* __restrict__ style1, float* __restrict__ tproj)
{
  int blk = blockIdx.x, t = threadIdx.x;
  if (blk < 2304) {                       // dcn pack: e=((k*32+c8)*256+o)*8+j
    int e = blk*256 + t;
    int j = e & 7, o = (e >> 3) & 255, c8 = (e >> 11) & 31, k = e >> 16;
    wtd[e] = f2bf(dcn_w[((o*256 + c8*8 + j)*9) + k]);
  } else if (blk < 4608) {                // conv1 pack
    int e = (blk-2304)*256 + t;
    int j = e & 7, o = (e >> 3) & 255, c8 = (e >> 11) & 31, k = e >> 16;
    wtc[e] = f2bf(c1w[((o*256 + c8*8 + j)*9) + k]);
  } else if (blk < 4896) {                // offw pack: [9][32 c8][32 o][8 j], oc>=27 -> 0
    int e = (blk-4608)*256 + t;           // 73728 elems
    int j = e & 7, o = (e >> 3) & 31, c8 = (e >> 8) & 31, k = e >> 13;
    int c = c8*8 + j;
    offwtb[e] = (o < 27) ? f2bf(offw[((o*256 + c)*9) + k]) : (unsigned short)0;
  } else if (blk < 4912) {                // style0 = zemb @ g0w.T + g0b (8x512)
    int e = (blk-4896)*256 + t; int b = e >> 9, j = e & 511;
    float s = g0b[j];
    const float* z = zemb + b*256; const float* w = g0w + j*256;
    for (int i = 0; i < 256; ++i) s += z[i]*w[i];
    style0[e] = s;
  } else if (blk < 4928) {                // style1
    int e = (blk-4912)*256 + t; int b = e >> 9, j = e & 511;
    float s = g1b[j];
    const float* z = zemb + b*256; const float* w = g1w + j*256;
    for (int i = 0; i < 256; ++i) s += z[i]*w[i];
    style1[e] = s;
  } else {                                // tproj = silu(temb) @ d0w.T + d0b (8x256)
    int e = (blk-4928)*256 + t; int b = e >> 8, o = e & 255;
    float s = d0b[o];
    const float* tb = temb + b*512; const float* w = d0w + o*512;
    for (int i = 0; i < 512; ++i) s += silu_f(tb[i])*w[i];
    tproj[e] = s;
  }
}

// ---------- reductions ----------
__device__ __forceinline__ void block_reduce2(float& s, float& q){
  for (int off = 32; off > 0; off >>= 1) {
    s += __shfl_down(s, off, 64);
    q += __shfl_down(q, off, 64);
  }
  __shared__ float ss[4], qs[4];
  int wid = threadIdx.x >> 6, lane = threadIdx.x & 63;
  if (lane == 0) { ss[wid] = s; qs[wid] = q; }
  __syncthreads();
  if (threadIdx.x == 0) { s = ss[0]+ss[1]+ss[2]+ss[3]; q = qs[0]+qs[1]+qs[2]+qs[3]; }
}

__global__ __launch_bounds__(256) void gn0_stats_kernel(
    const float* __restrict__ x, float* __restrict__ mu, float* __restrict__ rs)
{
  int blk = blockIdx.x;  // b*32+g ; NCHW group = 32768 contiguous
  const float4* p4 = (const float4*)(x + (size_t)blk*32768);
  float s = 0.f, q = 0.f;
  for (int i = threadIdx.x; i < 8192; i += 256) {
    float4 v = p4[i];
    s += v.x+v.y+v.z+v.w;
    q += v.x*v.x + v.y*v.y + v.z*v.z + v.w*v.w;
  }
  block_reduce2(s, q);
  if (threadIdx.x == 0) {
    float m = s * (1.f/32768.f);
    float var = q * (1.f/32768.f) - m*m;
    mu[blk] = m; rs[blk] = rsqrtf(var + EPSV);
  }
}

// GN stats over h1b (bf16 NHWC)
__global__ __launch_bounds__(256) void gn1_stats_kernel(
    const unsigned short* __restrict__ h1b, float* __restrict__ mu, float* __restrict__ rs)
{
  int blk = blockIdx.x;  // b*32+g
  int b = blk >> 5, g = blk & 31;
  const unsigned short* base = h1b + (size_t)b*1048576 + g*8;
  float s = 0.f, q = 0.f;
  for (int px = threadIdx.x; px < 4096; px += 256) {
    bf16x8 v = *(const bf16x8*)(base + (size_t)px*256);
    #pragma unroll
    for (int e = 0; e < 8; ++e) {
      float f = bf2f((unsigned short)v[e]);
      s += f; q += f*f;
    }
  }
  block_reduce2(s, q);
  if (threadIdx.x == 0) {
    float m = s * (1.f/32768.f);
    float var = q * (1.f/32768.f) - m*m;
    mu[blk] = m; rs[blk] = rsqrtf(var + EPSV);
  }
}

// ---------- h0 = silu(adagn(x)) NCHW -> NHWC bf16 ----------
__global__ __launch_bounds__(256) void h0_kernel(
    const float* __restrict__ x, const float* __restrict__ style0,
    const float* __restrict__ mu, const float* __restrict__ rs,
    unsigned short* __restrict__ h0b)
{
  int blk = blockIdx.x;          // b(8) x ptile(64) x ctile(8)
  int b  = blk >> 9;
  int pt = (blk >> 3) & 63;
  int ct = blk & 7;
  __shared__ float tile[32][65];
  int p0 = pt*64, c0 = ct*32;
  int t = threadIdx.x;
  for (int it = 0; it < 8; ++it) {
    int c = c0 + it*4 + (t >> 6);
    int p = p0 + (t & 63);
    float v = x[((size_t)(b*256 + c))*4096 + p];
    int g = c >> 3;
    float m  = mu[b*32+g], r = rs[b*32+g];
    float ga = style0[b*512 + c], be = style0[b*512 + 256 + c];
    float u = ga * (v - m) * r + be;
    tile[c - c0][p - p0] = silu_f(u);
  }
  __syncthreads();
  for (int it = 0; it < 8; ++it) {
    int pp = it*8 + (t >> 5);
    int cc = t & 31;
    h0b[((size_t)(b*4096 + p0 + pp))*256 + c0 + cc] = f2bf(tile[cc][pp]);
  }
}

// ---------- offset conv MFMA: 32 px x 32 oc (27 used), K=2304 ----------
__global__ __launch_bounds__(256) void offset_mfma_kernel(
    const unsigned short* __restrict__ h0b, const unsigned short* __restrict__ wt,
    const float* __restrict__ off_b, float* __restrict__ off_t)
{
  int bid = blockIdx.x;
  int b  = bid & 7;                            // XCD swizzle
  int p0 = (bid >> 3) * 32;
  int y = p0 >> 6, xb = p0 & 63;
  int t = threadIdx.x;
  int lane = t & 63, wv = t >> 6;
  int r = lane & 15, g = lane >> 4;

  __shared__ unsigned short aw[3*34*264];      // rows y-1..y+1, px xb-1..xb+32

  const unsigned short* hbase = h0b + (size_t)b*1048576;
  for (int idx = t; idx < 3264; idx += 256) {
    int row = idx / 1088, rem = idx - row*1088;
    int px = rem >> 5, c8 = rem & 31;
    int yy = y + row - 1, xx = xb - 1 + px;
    bf16x8 v = {0,0,0,0,0,0,0,0};
    if (yy >= 0 && yy < 64 && xx >= 0 && xx < 64)
      v = *(const bf16x8*)&hbase[((size_t)yy*64 + xx)*256 + c8*8];
    *(bf16x8*)&aw[(row*34 + px)*264 + c8*8] = v;
  }
  __syncthreads();

  int m = wv & 1, n = wv >> 1;                 // wave -> (px half, oc half)
  f32x4 acc = {0.f,0.f,0.f,0.f};
  for (int k = 0; k < 9; ++k) {
    int ky = k/3, kxo = k%3;
    const unsigned short* abase = &aw[(ky*34)*264];
    const unsigned short* wk = wt + (size_t)k*8192;   // [32 c8][32 o][8]
    #pragma unroll
    for (int kc = 0; kc < 8; ++kc) {
      bf16x8 a = *(const bf16x8*)&abase[(kxo + m*16 + r)*264 + kc*32 + g*8];
      bf16x8 bf = *(const bf16x8*)&wk[(size_t)((kc*4 + g)*32 + n*16 + r)*8];
      acc = __builtin_amdgcn_mfma_f32_16x16x32_bf16(a, bf, acc, 0, 0, 0);
    }
  }

  int oc = n*16 + r;
  if (oc < 27) {
    float bs = off_b[oc];
    #pragma unroll
    for (int j = 0; j < 4; ++j) {
      int px = m*16 + g*4 + j;
      off_t[((size_t)(b*4096) + p0 + px)*27 + oc] = acc[j] + bs;
    }
  }
}

// ---------- deformable conv, MFMA, M=64 row, 8 waves x unique 32-out ----------
__global__ __launch_bounds__(512, 2) void deform_mfma_kernel(
    const unsigned short* __restrict__ h0b, const float* __restrict__ off_t,
    const unsigned short* __restrict__ wt, const float* __restrict__ dcn_b,
    const float* __restrict__ tproj, unsigned short* __restrict__ h1b)
{
  int bid = blockIdx.x;
  int b  = bid & 7;                            // XCD swizzle (512 % 8 == 0)
  int p0 = (bid >> 3) * 64;                    // one full image row
  int t = threadIdx.x;                         // 0..511
  int lane = t & 63, wv = t >> 6;              // 8 waves
  int r = lane & 15, g = lane >> 4;

  __shared__ unsigned short samp[2][64*264];   // dbuf [px][264] bf16 (67.6KB)
  __shared__ int   iy0s[576], ix0s[576], iy1s[576], ix1s[576];
  __shared__ float w00s[576], w01s[576], w10s[576], w11s[576];

  for (int tp = t; tp < 576; tp += 512) {      // 64 px x 9 taps
    int i = tp / 9, k = tp - i*9;
    int p = p0 + i; int y = p >> 6, xq = p & 63;
    const float* ob = off_t + ((size_t)(b*4096) + p)*27;
    float dy = ob[2*k], dx = ob[2*k+1];
    float mask = 1.f / (1.f + __expf(-ob[18+k]));
    float py = dy + (float)(k/3 + y - 1);
    float px = dx + (float)(k%3 + xq - 1);
    float fy0 = floorf(py), fx0 = floorf(px);
    float wy1 = py - fy0, wx1 = px - fx0;
    int y0 = (int)fy0, x0 = (int)fx0, y1 = y0+1, x1 = x0+1;
    float vy0 = (y0 >= 0 && y0 < 64) ? 1.f : 0.f;
    float vy1 = (y1 >= 0 && y1 < 64) ? 1.f : 0.f;
    float vx0 = (x0 >= 0 && x0 < 64) ? 1.f : 0.f;
    float vx1 = (x1 >= 0 && x1 < 64) ? 1.f : 0.f;
    iy0s[tp] = min(max(y0,0),63); ix0s[tp] = min(max(x0,0),63);
    iy1s[tp] = min(max(y1,0),63); ix1s[tp] = min(max(x1,0),63);
    w00s[tp] = (1.f-wy1)*(1.f-wx1)*vy0*vx0*mask;
    w01s[tp] = (1.f-wy1)*wx1      *vy0*vx1*mask;
    w10s[tp] = wy1      *(1.f-wx1)*vy1*vx0*mask;
    w11s[tp] = wy1      *wx1      *vy1*vx1*mask;
  }
  __syncthreads();

  f32x4 zero4 = {0.f,0.f,0.f,0.f};
  f32x4 acc[4][2];
  #pragma unroll
  for (int m = 0; m < 4; ++m) { acc[m][0] = zero4; acc[m][1] = zero4; }

  const unsigned short* hb = h0b + (size_t)b*1048576;
  int px = t >> 3;                             // 8 threads per pixel (64 px)
  int ci = (t & 7) * 32;                       // 32 contiguous channels each
  int o_base = wv*32 + r;                      // 8 waves x UNIQUE 32-out slice

  bf16x8 pre[16];                              // 4 corners x 32ch (64 VGPR, cap 256)
  auto loadk = [&](int kk) {
    int tp = px*9 + kk;
    const bf16x8* q00 = (const bf16x8*)(hb + ((size_t)iy0s[tp]*64 + ix0s[tp])*256 + ci);
    const bf16x8* q01 = (const bf16x8*)(hb + ((size_t)iy0s[tp]*64 + ix1s[tp])*256 + ci);
    const bf16x8* q10 = (const bf16x8*)(hb + ((size_t)iy1s[tp]*64 + ix0s[tp])*256 + ci);
    const bf16x8* q11 = (const bf16x8*)(hb + ((size_t)iy1s[tp]*64 + ix1s[tp])*256 + ci);
    pre[0] = q00[0]; pre[1] = q00[1]; pre[2] = q00[2]; pre[3] = q00[3];
    pre[4] = q01[0]; pre[5] = q01[1]; pre[6] = q01[2]; pre[7] = q01[3];
    pre[8] = q10[0]; pre[9] = q10[1]; pre[10] = q10[2]; pre[11] = q10[3];
    pre[12] = q11[0]; pre[13] = q11[1]; pre[14] = q11[2]; pre[15] = q11[3];
  };

  loadk(0);
  for (int k = 0; k < 9; ++k) {
    { // cvt + weighted sum from prefetch regs -> LDS buf k&1
      int tp = px*9 + k;
      float a00 = w00s[tp], a01 = w01s[tp], a10 = w10s[tp], a11 = w11s[tp];
      unsigned short* sp = &samp[k & 1][px*264 + ci];
      #pragma unroll
      for (int ch = 0; ch < 4; ++ch) {
        bf16x8 o;
        #pragma unroll
        for (int e = 0; e < 8; ++e) {
          float v = a00*bf2f((unsigned short)pre[ch][e])
                  + a01*bf2f((unsigned short)pre[4+ch][e])
                  + a10*bf2f((unsigned short)pre[8+ch][e])
                  + a11*bf2f((unsigned short)pre[12+ch][e]);
          o[e] = (short)f2bf(v);
        }
        *(bf16x8*)(sp + ch*8) = o;
      }
    }
    if (k < 8) loadk(k+1);                     // next-tap loads hide under MFMA
    __syncthreads();                           // ONE barrier per tap (dbuf)

    const unsigned short* sb = samp[k & 1];
    const unsigned short* wk = wt + (size_t)k*65536;   // [32][256][8] this tap
    #pragma unroll
    for (int kc = 0; kc < 8; ++kc) {
      bf16x8 a0 = *(const bf16x8*)&sb[(     r)*264 + kc*32 + g*8];
      bf16x8 a1 = *(const bf16x8*)&sb[(16 + r)*264 + kc*32 + g*8];
      bf16x8 a2 = *(const bf16x8*)&sb[(32 + r)*264 + kc*32 + g*8];
      bf16x8 a3 = *(const bf16x8*)&sb[(48 + r)*264 + kc*32 + g*8];
      const unsigned short* wb = wk + (size_t)(kc*4 + g)*2048 + o_base*8;
      bf16x8 b0 = *(const bf16x8*)&wb[  0*8];
      bf16x8 b1 = *(const bf16x8*)&wb[ 16*8];
      acc[0][0] = __builtin_amdgcn_mfma_f32_16x16x32_bf16(a0, b0, acc[0][0], 0, 0, 0);
      acc[0][1] = __builtin_amdgcn_mfma_f32_16x16x32_bf16(a0, b1, acc[0][1], 0, 0, 0);
      acc[1][0] = __builtin_amdgcn_mfma_f32_16x16x32_bf16(a1, b0, acc[1][0], 0, 0, 0);
      acc[1][1] = __builtin_amdgcn_mfma_f32_16x16x32_bf16(a1, b1, acc[1][1], 0, 0, 0);
      acc[2][0] = __builtin_amdgcn_mfma_f32_16x16x32_bf16(a2, b0, acc[2][0], 0, 0, 0);
      acc[2][1] = __builtin_amdgcn_mfma_f32_16x16x32_bf16(a2, b1, acc[2][1], 0, 0, 0);
      acc[3][0] = __builtin_amdgcn_mfma_f32_16x16x32_bf16(a3, b0, acc[3][0], 0, 0, 0);
      acc[3][1] = __builtin_amdgcn_mfma_f32_16x16x32_bf16(a3, b1, acc[3][1], 0, 0, 0);
    }
    // no second barrier: next tap writes the other buffer
  }

  #pragma unroll
  for (int nn = 0; nn < 2; ++nn) {
    int o = o_base + nn*16;
    float bs = dcn_b[o] + tproj[b*256 + o];
    #pragma unroll
    for (int m = 0; m < 4; ++m)
      #pragma unroll
      for (int j = 0; j < 4; ++j) {
        int pxl = m*16 + g*4 + j;
        h1b[((size_t)(b*4096) + p0 + pxl)*256 + o] = f2bf(acc[m][nn][j] + bs);
      }
  }
}

// ---------- h2 = silu(adagn(h1b)) -> bf16 NHWC ----------
__global__ __launch_bounds__(256) void h2_bf16_kernel(
    const unsigned short* __restrict__ h1b, const float* __restrict__ style1,
    const float* __restrict__ mu, const float* __restrict__ rs,
    unsigned short* __restrict__ h2b)
{
  size_t i = ((size_t)blockIdx.x*256 + threadIdx.x)*8;
  bf16x8 v = *(const bf16x8*)(h1b + i);
  int b = (int)(i >> 20);
  int c0 = (int)(i & 255);
  int g = c0 >> 3;
  float m  = mu[b*32+g], rr = rs[b*32+g];
  bf16x8 o;
  #pragma unroll
  for (int j = 0; j < 8; ++j) {
    int c = c0 + j;
    float ga = style1[b*512 + c], be = style1[b*512 + 256 + c];
    float u = ga * (bf2f((unsigned short)v[j]) - m) * rr + be;
    o[j] = (short)f2bf(silu_f(u));
  }
  *(bf16x8*)(h2b + i) = o;
}

// ---------- conv1 3x3 MFMA + residual, M=64 row, 8 waves x 32-out ----------
__global__ __launch_bounds__(512, 2) void conv1_mfma_kernel(
    const unsigned short* __restrict__ h2b, const unsigned short* __restrict__ wt,
    const float* __restrict__ c1_b, const float* __restrict__ x,
    float* __restrict__ out)
{
  int bid = blockIdx.x;
  int b  = bid & 7;                            // XCD swizzle (512 % 8 == 0)
  int p0 = (bid >> 3) * 64;                    // one full image row
  int y = p0 >> 6;
  int t = threadIdx.x;                         // 0..511
  int lane = t & 63, wv = t >> 6;              // 8 waves
  int r = lane & 15, g = lane >> 4;

  __shared__ unsigned short aw[3*66*264];      // rows y-1..y+1, px -1..64 (102KB)

  const unsigned short* h2base = h2b + (size_t)b*1048576;
  for (int idx = t; idx < 6336; idx += 512) {  // 3 rows * 66 px * 32 chunks
    int row = idx / 2112, rem = idx - row*2112;
    int px = rem >> 5, c8 = rem & 31;
    int yy = y + row - 1, xx = px - 1;
    bf16x8 v = {0,0,0,0,0,0,0,0};
    if (yy >= 0 && yy < 64 && xx >= 0 && xx < 64)
      v = *(const bf16x8*)&h2base[((size_t)yy*64 + xx)*256 + c8*8];
    *(bf16x8*)&aw[(row*66 + px)*264 + c8*8] = v;
  }
  __syncthreads();

  f32x4 zero4 = {0.f,0.f,0.f,0.f};
  f32x4 acc[4][2];
  #pragma unroll
  for (int m = 0; m < 4; ++m) { acc[m][0] = zero4; acc[m][1] = zero4; }

  int o_base = wv*32 + r;                      // 8 waves x UNIQUE 32-out slice
  for (int k = 0; k < 9; ++k) {
    int ky = k/3, kxo = k%3;
    const unsigned short* abase = &aw[(ky*66)*264];
    const unsigned short* wk = wt + (size_t)k*65536;
    #pragma unroll
    for (int kc = 0; kc < 8; ++kc) {
      bf16x8 a0 = *(const bf16x8*)&abase[(kxo +      r)*264 + kc*32 + g*8];
      bf16x8 a1 = *(const bf16x8*)&abase[(kxo + 16 + r)*264 + kc*32 + g*8];
      bf16x8 a2 = *(const bf16x8*)&abase[(kxo + 32 + r)*264 + kc*32 + g*8];
      bf16x8 a3 = *(const bf16x8*)&abase[(kxo + 48 + r)*264 + kc*32 + g*8];
      const unsigned short* wb = wk + (size_t)(kc*4 + g)*2048 + o_base*8;
      bf16x8 b0 = *(const bf16x8*)&wb[  0*8];
      bf16x8 b1 = *(const bf16x8*)&wb[ 16*8];
      acc[0][0] = __builtin_amdgcn_mfma_f32_16x16x32_bf16(a0, b0, acc[0][0], 0, 0, 0);
      acc[0][1] = __builtin_amdgcn_mfma_f32_16x16x32_bf16(a0, b1, acc[0][1], 0, 0, 0);
      acc[1][0] = __builtin_amdgcn_mfma_f32_16x16x32_bf16(a1, b0, acc[1][0], 0, 0, 0);
      acc[1][1] = __builtin_amdgcn_mfma_f32_16x16x32_bf16(a1, b1, acc[1][1], 0, 0, 0);
      acc[2][0] = __builtin_amdgcn_mfma_f32_16x16x32_bf16(a2, b0, acc[2][0], 0, 0, 0);
      acc[2][1] = __builtin_amdgcn_mfma_f32_16x16x32_bf16(a2, b1, acc[2][1], 0, 0, 0);
      acc[3][0] = __builtin_amdgcn_mfma_f32_16x16x32_bf16(a3, b0, acc[3][0], 0, 0, 0);
      acc[3][1] = __builtin_amdgcn_mfma_f32_16x16x32_bf16(a3, b1, acc[3][1], 0, 0, 0);
    }
  }

  #pragma unroll
  for (int nn = 0; nn < 2; ++nn) {
    int o = o_base + nn*16;
    float cb = c1_b[o];
    #pragma unroll
    for (int m = 0; m < 4; ++m)
      #pragma unroll
      for (int j = 0; j < 4; ++j) {
        int pxl = m*16 + g*4 + j;
        size_t oi = ((size_t)(b*256 + o))*4096 + p0 + pxl;
        out[oi] = x[oi] + acc[m][nn][j] + cb;
      }
  }
}

extern "C" void kernel_launch(void* const* d_in, const int* in_sizes, int n_in,
                              void* d_out, int out_size, void* d_ws, size_t ws_size,
                              hipStream_t stream) {
  const float* x    = (const float*)d_in[0];
  const float* temb = (const float*)d_in[1];
  const float* zemb = (const float*)d_in[2];
  const float* g0w  = (const float*)d_in[3];
  const float* g0b  = (const float*)d_in[4];
  const float* offw = (const float*)d_in[5];
  const float* offb = (const float*)d_in[6];
  const float* dcnw = (const float*)d_in[7];
  const float* dcnb = (const float*)d_in[8];
  const float* d0w  = (const float*)d_in[9];
  const float* d0b  = (const float*)d_in[10];
  const float* g1w  = (const float*)d_in[11];
  const float* g1b  = (const float*)d_in[12];
  const float* c1w  = (const float*)d_in[13];
  const float* c1b  = (const float*)d_in[14];
  float* out = (float*)d_out;
  float* ws  = (float*)d_ws;

  unsigned short* h0b = (unsigned short*)(ws + WS_H0B);
  unsigned short* h1b = (unsigned short*)(ws + WS_H1B);
  float* off_t   = ws + WS_OFFT;
  unsigned short* wtd  = (unsigned short*)(ws + WS_WTD);
  unsigned short* wtc  = (unsigned short*)(ws + WS_WTC);
  unsigned short* owtb = (unsigned short*)(ws + WS_OFFWTB);
  float* style0  = ws + WS_STYLE0;
  float* style1  = ws + WS_STYLE1;
  float* tproj   = ws + WS_TPROJ;
  float* mu0     = ws + WS_MU0;
  float* rs0     = ws + WS_RS0;
  float* mu1     = ws + WS_MU1;
  float* rs1     = ws + WS_RS1;
  unsigned short* h2b = (unsigned short*)(ws + WS_H0B);  // reuse (h0 dead after deform)

  prep_kernel<<<4936, 256, 0, stream>>>(zemb, temb, g0w, g0b, g1w, g1b, d0w, d0b,
                                        dcnw, c1w, offw, wtd, wtc, owtb,
                                        style0, style1, tproj);
  gn0_stats_kernel<<<256, 256, 0, stream>>>(x, mu0, rs0);
  h0_kernel<<<4096, 256, 0, stream>>>(x, style0, mu0, rs0, h0b);
  offset_mfma_kernel<<<1024, 256, 0, stream>>>(h0b, owtb, offb, off_t);
  deform_mfma_kernel<<<512, 512, 0, stream>>>(h0b, off_t, wtd, dcnb, tproj, h1b);
  gn1_stats_kernel<<<256, 256, 0, stream>>>(h1b, mu1, rs1);
  h2_bf16_kernel<<<4096, 256, 0, stream>>>(h1b, style1, mu1, rs1, h2b);
  conv1_mfma_kernel<<<512, 512, 0, stream>>>(h2b, wtc, c1b, x, out);
}